// Round 2
// baseline (837.391 us; speedup 1.0000x reference)
//
#include <hip/hip_runtime.h>
#include <math.h>

// Problem constants (fixed by the reference)
#define NN   100000           // nodes
#define NE   1600000          // edges (before self-loops)
#define E2   (NE + NN)        // edges incl. self-loops = 1,700,000
#define FIN  128
#define F1   128              // HEADS*HID
#define NC   40
#define NEG  0.2f

// NOTE: parameter names must not collide with .x/.y/.z/.w member tokens —
// the preprocessor substitutes them even after '.', which broke round 0.
#define FMA4(acc_, s_, w_) { (acc_).x = fmaf((s_),(w_).x,(acc_).x); (acc_).y = fmaf((s_),(w_).y,(acc_).y); \
                             (acc_).z = fmaf((s_),(w_).z,(acc_).z); (acc_).w = fmaf((s_),(w_).w,(acc_).w); }

// ---------------- GEMM1: h1 = x @ W1   [NN,128] x [128,128] ----------------
// W1 (64KB) staged in LDS. Thread computes 4 rows x 4 cols (register blocking)
// -> 8 FMA per LDS b128 read: compute-bound, not LDS-bound.
__global__ __launch_bounds__(256) void gemm1_kernel(const float* __restrict__ x,
                                                    const float* __restrict__ W,
                                                    float* __restrict__ h1) {
    __shared__ float Ws[128 * 128];            // exactly 64 KiB
    const float4* W4 = (const float4*)W;
    float4* Ws4 = (float4*)Ws;
    for (int i = threadIdx.x; i < 128 * 128 / 4; i += 256) Ws4[i] = W4[i];
    __syncthreads();

    int cg = threadIdx.x & 31;                 // cols 4cg..4cg+3
    int rg = threadIdx.x >> 5;                 // 8 row groups x 4 rows
    int row0 = blockIdx.x * 32 + rg * 4;       // 3125 blocks * 32 rows = 100000 exact
    const float4* x4 = (const float4*)x;

    float4 acc[4];
    acc[0] = acc[1] = acc[2] = acc[3] = make_float4(0.f, 0.f, 0.f, 0.f);

    for (int k4 = 0; k4 < 32; ++k4) {
        float4 wv0 = Ws4[(k4 * 4 + 0) * 32 + cg];   // lanes read consecutive 16B: conflict-free
        float4 wv1 = Ws4[(k4 * 4 + 1) * 32 + cg];
        float4 wv2 = Ws4[(k4 * 4 + 2) * 32 + cg];
        float4 wv3 = Ws4[(k4 * 4 + 3) * 32 + cg];
#pragma unroll
        for (int r = 0; r < 4; ++r) {
            float4 xv = x4[(row0 + r) * 32 + k4];   // broadcast within row group -> L1
            FMA4(acc[r], xv.x, wv0);
            FMA4(acc[r], xv.y, wv1);
            FMA4(acc[r], xv.z, wv2);
            FMA4(acc[r], xv.w, wv3);
        }
    }
    float4* o4 = (float4*)h1;
#pragma unroll
    for (int r = 0; r < 4; ++r) o4[(row0 + r) * 32 + cg] = acc[r];
}

// ---------------- GEMM2: h2 = helu @ W2   [NN,128] x [128,40] ----------------
__global__ __launch_bounds__(256) void gemm2_kernel(const float* __restrict__ xin,
                                                    const float* __restrict__ W,
                                                    float* __restrict__ h2) {
    __shared__ float Ws[128 * 40];             // 20 KiB
    const float4* W4 = (const float4*)W;
    float4* Ws4 = (float4*)Ws;
    for (int i = threadIdx.x; i < 128 * 40 / 4; i += 256) Ws4[i] = W4[i];
    __syncthreads();

    int t = threadIdx.x;
    if (t >= 250) return;                       // 10 col groups x 25 row groups
    int cg = t % 10;                            // cols 4cg..4cg+3
    int rg = t / 10;
    int row0 = blockIdx.x * 100 + rg * 4;       // 1000 blocks * 100 rows = 100000 exact
    const float4* x4 = (const float4*)xin;

    float4 acc[4];
    acc[0] = acc[1] = acc[2] = acc[3] = make_float4(0.f, 0.f, 0.f, 0.f);

    for (int k4 = 0; k4 < 32; ++k4) {
        float4 wv0 = Ws4[(k4 * 4 + 0) * 10 + cg];
        float4 wv1 = Ws4[(k4 * 4 + 1) * 10 + cg];
        float4 wv2 = Ws4[(k4 * 4 + 2) * 10 + cg];
        float4 wv3 = Ws4[(k4 * 4 + 3) * 10 + cg];
#pragma unroll
        for (int r = 0; r < 4; ++r) {
            float4 xv = x4[(row0 + r) * 32 + k4];
            FMA4(acc[r], xv.x, wv0);
            FMA4(acc[r], xv.y, wv1);
            FMA4(acc[r], xv.z, wv2);
            FMA4(acc[r], xv.w, wv3);
        }
    }
    float4* o4 = (float4*)h2;                   // 40 floats/row = 10 float4
#pragma unroll
    for (int r = 0; r < 4; ++r) o4[(row0 + r) * 10 + cg] = acc[r];
}

// ---------------- per-node attention scalars ----------------
// al_s[n][h] = sum_c h[n][h][c]*a_src[h][c]; one wave per row.
__global__ __launch_bounds__(256) void al1_kernel(const float* __restrict__ h1,
                                                  const float* __restrict__ a_s,
                                                  const float* __restrict__ a_d,
                                                  float* __restrict__ als,
                                                  float* __restrict__ ald) {
    int lane = threadIdx.x & 63;
    int row = blockIdx.x * 4 + (threadIdx.x >> 6);
    float v0 = h1[row * 128 + lane];
    float v1 = h1[row * 128 + 64 + lane];
    float s0 = v0 * a_s[lane],      s1 = v1 * a_s[64 + lane];
    float d0 = v0 * a_d[lane],      d1 = v1 * a_d[64 + lane];
    for (int m = 32; m; m >>= 1) {
        s0 += __shfl_xor(s0, m); s1 += __shfl_xor(s1, m);
        d0 += __shfl_xor(d0, m); d1 += __shfl_xor(d1, m);
    }
    if (lane == 0) {
        als[row * 2] = s0; als[row * 2 + 1] = s1;
        ald[row * 2] = d0; ald[row * 2 + 1] = d1;
    }
}

__global__ __launch_bounds__(256) void al2_kernel(const float* __restrict__ h2,
                                                  const float* __restrict__ a_s,
                                                  const float* __restrict__ a_d,
                                                  float* __restrict__ als,
                                                  float* __restrict__ ald) {
    int lane = threadIdx.x & 63;
    int row = blockIdx.x * 4 + (threadIdx.x >> 6);
    float v  = (lane < NC) ? h2[row * 40 + lane] : 0.f;
    float as_ = (lane < NC) ? a_s[lane] : 0.f;
    float ad_ = (lane < NC) ? a_d[lane] : 0.f;
    float s = v * as_, d = v * ad_;
    for (int m = 32; m; m >>= 1) { s += __shfl_xor(s, m); d += __shfl_xor(d, m); }
    if (lane == 0) { als[row] = s; ald[row] = d; }
}

// ---------------- CSR build (by dst) ----------------
__global__ __launch_bounds__(256) void count_kernel(const int* __restrict__ ei,
                                                    int* __restrict__ deg) {
    int j = blockIdx.x * 256 + threadIdx.x;
    if (j >= E2) return;
    int d = (j < NE) ? ei[NE + j] : (j - NE);
    atomicAdd(&deg[d], 1);
}

__global__ __launch_bounds__(256) void scan1_kernel(const int* __restrict__ deg,
                                                    int* __restrict__ offs,
                                                    int* __restrict__ bsum) {
    __shared__ int sh[256];
    int base = blockIdx.x * 1024 + threadIdx.x * 4;
    int v[4];
#pragma unroll
    for (int u = 0; u < 4; ++u) { int idx = base + u; v[u] = (idx < NN) ? deg[idx] : 0; }
    int t0 = v[0] + v[1] + v[2] + v[3];
    sh[threadIdx.x] = t0;
    __syncthreads();
    for (int off = 1; off < 256; off <<= 1) {
        int a = sh[threadIdx.x];
        int b = (threadIdx.x >= off) ? sh[threadIdx.x - off] : 0;
        __syncthreads();
        sh[threadIdx.x] = a + b;
        __syncthreads();
    }
    int excl = sh[threadIdx.x] - t0;
    if (threadIdx.x == 255) bsum[blockIdx.x] = sh[255];
    int run = excl;
#pragma unroll
    for (int u = 0; u < 4; ++u) { int idx = base + u; if (idx < NN) offs[idx] = run; run += v[u]; }
}

__global__ void scan2_kernel(int* __restrict__ bsum, int* __restrict__ offs) {
    __shared__ int sh[128];
    int i = threadIdx.x;                        // 128 threads, 98 blocks' sums
    int v = (i < 98) ? bsum[i] : 0;
    sh[i] = v;
    __syncthreads();
    for (int off = 1; off < 128; off <<= 1) {
        int a = sh[i];
        int b = (i >= off) ? sh[i - off] : 0;
        __syncthreads();
        sh[i] = a + b;
        __syncthreads();
    }
    if (i < 98) bsum[i] = sh[i] - v;            // exclusive
    if (i == 127) offs[NN] = sh[127];           // total = E2
}

__global__ __launch_bounds__(256) void scan3_kernel(int* __restrict__ offs,
                                                    const int* __restrict__ bsum) {
    int i = blockIdx.x * 256 + threadIdx.x;
    if (i < NN) offs[i] += bsum[i >> 10];
}

__global__ __launch_bounds__(256) void place_kernel(const int* __restrict__ ei,
                                                    const int* __restrict__ offs,
                                                    int* __restrict__ cur,
                                                    int* __restrict__ csr) {
    int j = blockIdx.x * 256 + threadIdx.x;
    if (j >= E2) return;
    int s, d;
    if (j < NE) { s = ei[j]; d = ei[NE + j]; } else { s = d = j - NE; }
    int p = offs[d] + atomicAdd(&cur[d], 1);
    csr[p] = s;
}

// ---------------- Aggregation layer 1 (+bias +ELU) ----------------
// One wave per dst node. 3 passes: max, sum-of-exp, weighted gather.
__global__ __launch_bounds__(256) void agg1_kernel(const int* __restrict__ offs,
                                                   const int* __restrict__ csr,
                                                   const float* __restrict__ als,
                                                   const float* __restrict__ ald,
                                                   const float* __restrict__ h1,
                                                   const float* __restrict__ b,
                                                   float* __restrict__ helu) {
    int lane = threadIdx.x & 63;
    int node = blockIdx.x * 4 + (threadIdx.x >> 6);
    int start = offs[node], end = offs[node + 1];
    float ad0 = ald[node * 2], ad1 = ald[node * 2 + 1];

    float m0 = -1e30f, m1 = -1e30f;
    for (int j = start + lane; j < end; j += 64) {
        int s = csr[j];
        float e0 = als[s * 2] + ad0;     e0 = e0 > 0.f ? e0 : NEG * e0;
        float e1 = als[s * 2 + 1] + ad1; e1 = e1 > 0.f ? e1 : NEG * e1;
        m0 = fmaxf(m0, e0); m1 = fmaxf(m1, e1);
    }
    for (int m = 32; m; m >>= 1) { m0 = fmaxf(m0, __shfl_xor(m0, m)); m1 = fmaxf(m1, __shfl_xor(m1, m)); }

    float s0 = 0.f, s1 = 0.f;
    for (int j = start + lane; j < end; j += 64) {
        int s = csr[j];
        float e0 = als[s * 2] + ad0;     e0 = e0 > 0.f ? e0 : NEG * e0;
        float e1 = als[s * 2 + 1] + ad1; e1 = e1 > 0.f ? e1 : NEG * e1;
        s0 += expf(e0 - m0); s1 += expf(e1 - m1);
    }
    for (int m = 32; m; m >>= 1) { s0 += __shfl_xor(s0, m); s1 += __shfl_xor(s1, m); }
    float inv0 = 1.f / (s0 + 1e-16f), inv1 = 1.f / (s1 + 1e-16f);

    float acc0 = 0.f, acc1 = 0.f;
    for (int j = start; j < end; ++j) {
        int s = csr[j];                               // broadcast (uniform across wave)
        float e0 = als[s * 2] + ad0;     e0 = e0 > 0.f ? e0 : NEG * e0;
        float e1 = als[s * 2 + 1] + ad1; e1 = e1 > 0.f ? e1 : NEG * e1;
        float w0 = expf(e0 - m0) * inv0, w1 = expf(e1 - m1) * inv1;
        acc0 = fmaf(w0, h1[s * 128 + lane], acc0);        // coalesced 256B
        acc1 = fmaf(w1, h1[s * 128 + 64 + lane], acc1);   // coalesced 256B
    }
    float o0 = acc0 + b[lane];
    float o1 = acc1 + b[64 + lane];
    o0 = o0 > 0.f ? o0 : expm1f(o0);                  // ELU
    o1 = o1 > 0.f ? o1 : expm1f(o1);
    helu[node * 128 + lane] = o0;
    helu[node * 128 + 64 + lane] = o1;
}

// ---------------- Aggregation layer 2 (+bias) fused with log_softmax ----------------
__global__ __launch_bounds__(256) void agg2_kernel(const int* __restrict__ offs,
                                                   const int* __restrict__ csr,
                                                   const float* __restrict__ als,
                                                   const float* __restrict__ ald,
                                                   const float* __restrict__ h2,
                                                   const float* __restrict__ b,
                                                   float* __restrict__ out) {
    int lane = threadIdx.x & 63;
    int node = blockIdx.x * 4 + (threadIdx.x >> 6);
    int start = offs[node], end = offs[node + 1];
    float ad = ald[node];

    float m = -1e30f;
    for (int j = start + lane; j < end; j += 64) {
        int s = csr[j];
        float e = als[s] + ad; e = e > 0.f ? e : NEG * e;
        m = fmaxf(m, e);
    }
    for (int mm = 32; mm; mm >>= 1) m = fmaxf(m, __shfl_xor(m, mm));

    float sum = 0.f;
    for (int j = start + lane; j < end; j += 64) {
        int s = csr[j];
        float e = als[s] + ad; e = e > 0.f ? e : NEG * e;
        sum += expf(e - m);
    }
    for (int mm = 32; mm; mm >>= 1) sum += __shfl_xor(sum, mm);
    float inv = 1.f / (sum + 1e-16f);

    float acc = 0.f;
    for (int j = start; j < end; ++j) {
        int s = csr[j];
        float e = als[s] + ad; e = e > 0.f ? e : NEG * e;
        float w = expf(e - m) * inv;
        if (lane < NC) acc = fmaf(w, h2[s * 40 + lane], acc);
    }
    float o = (lane < NC) ? acc + b[lane] : -1e30f;

    // log_softmax over the 40 classes (within wave)
    float mx = o;
    for (int mm = 32; mm; mm >>= 1) mx = fmaxf(mx, __shfl_xor(mx, mm));
    float ex = (lane < NC) ? expf(o - mx) : 0.f;
    float es = ex;
    for (int mm = 32; mm; mm >>= 1) es += __shfl_xor(es, mm);
    float lse = mx + logf(es);
    if (lane < NC) out[node * 40 + lane] = o - lse;
}

// ---------------- launch ----------------
extern "C" void kernel_launch(void* const* d_in, const int* in_sizes, int n_in,
                              void* d_out, int out_size, void* d_ws, size_t ws_size,
                              hipStream_t stream) {
    const float* x   = (const float*)d_in[0];
    const int*   ei  = (const int*)  d_in[1];
    const float* W1  = (const float*)d_in[2];
    const float* as1 = (const float*)d_in[3];
    const float* ad1 = (const float*)d_in[4];
    const float* b1  = (const float*)d_in[5];
    const float* W2  = (const float*)d_in[6];
    const float* as2 = (const float*)d_in[7];
    const float* ad2 = (const float*)d_in[8];
    const float* b2  = (const float*)d_in[9];
    float* out = (float*)d_out;

    // workspace carve-up
    char* p = (char*)d_ws;
    auto alloc = [&](size_t bytes) { void* r = (void*)p; p += (bytes + 255) & ~size_t(255); return r; };
    float* h1   = (float*)alloc(sizeof(float) * NN * 128);
    float* helu = (float*)alloc(sizeof(float) * NN * 128);
    float* h2   = (float*)alloc(sizeof(float) * NN * 40);
    float* als1 = (float*)alloc(sizeof(float) * NN * 2);
    float* ald1 = (float*)alloc(sizeof(float) * NN * 2);
    float* als2 = (float*)alloc(sizeof(float) * NN);
    float* ald2 = (float*)alloc(sizeof(float) * NN);
    int*   deg  = (int*)  alloc(sizeof(int) * NN);
    int*   offs = (int*)  alloc(sizeof(int) * (NN + 1));
    int*   bsum = (int*)  alloc(sizeof(int) * 128);
    int*   csr  = (int*)  alloc(sizeof(int) * E2);

    // CSR build (dst-sorted adjacency)
    hipMemsetAsync(deg, 0, sizeof(int) * NN, stream);
    count_kernel<<<(E2 + 255) / 256, 256, 0, stream>>>(ei, deg);
    scan1_kernel<<<98, 256, 0, stream>>>(deg, offs, bsum);
    scan2_kernel<<<1, 128, 0, stream>>>(bsum, offs);
    scan3_kernel<<<(NN + 255) / 256, 256, 0, stream>>>(offs, bsum);
    hipMemsetAsync(deg, 0, sizeof(int) * NN, stream);   // reuse as cursor
    place_kernel<<<(E2 + 255) / 256, 256, 0, stream>>>(ei, offs, deg, csr);

    // Layer 1
    gemm1_kernel<<<3125, 256, 0, stream>>>(x, W1, h1);
    al1_kernel<<<25000, 256, 0, stream>>>(h1, as1, ad1, als1, ald1);
    agg1_kernel<<<25000, 256, 0, stream>>>(offs, csr, als1, ald1, h1, b1, helu);

    // Layer 2
    gemm2_kernel<<<1000, 256, 0, stream>>>(helu, W2, h2);
    al2_kernel<<<25000, 256, 0, stream>>>(h2, as2, ad2, als2, ald2);
    agg2_kernel<<<25000, 256, 0, stream>>>(offs, csr, als2, ald2, h2, b2, out);
}

// Round 3
// 643.343 us; speedup vs baseline: 1.3016x; 1.3016x over previous
//
#include <hip/hip_runtime.h>
#include <math.h>

// Problem constants (fixed by the reference)
#define NN   100000           // nodes
#define NE   1600000          // edges (before self-loops)
#define E2   (NE + NN)        // edges incl. self-loops = 1,700,000
#define NC   40
#define NEG  0.2f
#define MAXD 128              // per-node LDS weight buffer (deg ~ Poisson(16)+1; P(>128) ~ 0)

// NOTE: macro parameter names must not collide with .x/.y/.z/.w member tokens.
#define FMA4(acc_, s_, w_) { (acc_).x = fmaf((s_),(w_).x,(acc_).x); (acc_).y = fmaf((s_),(w_).y,(acc_).y); \
                             (acc_).z = fmaf((s_),(w_).z,(acc_).z); (acc_).w = fmaf((s_),(w_).w,(acc_).w); }

// ---------------- GEMM1: h1 = x @ W1  [NN,128]x[128,128], fused al1 epilogue ----------------
__global__ __launch_bounds__(256) void gemm1_kernel(const float* __restrict__ x,
                                                    const float* __restrict__ W,
                                                    const float* __restrict__ a_s,
                                                    const float* __restrict__ a_d,
                                                    float* __restrict__ h1,
                                                    float* __restrict__ als,
                                                    float* __restrict__ ald) {
    __shared__ float Ws[128 * 128];            // 64 KiB
    const float4* W4 = (const float4*)W;
    float4* Ws4 = (float4*)Ws;
    for (int i = threadIdx.x; i < 128 * 128 / 4; i += 256) Ws4[i] = W4[i];
    __syncthreads();

    int cg = threadIdx.x & 31;                 // cols 4cg..4cg+3
    int rg = threadIdx.x >> 5;                 // 8 row groups x 4 rows
    int lane = threadIdx.x & 63;
    int row0 = blockIdx.x * 32 + rg * 4;       // 3125 blocks
    const float4* x4 = (const float4*)x;

    float4 acc[4];
    acc[0] = acc[1] = acc[2] = acc[3] = make_float4(0.f, 0.f, 0.f, 0.f);

    for (int k4 = 0; k4 < 32; ++k4) {
        float4 wv0 = Ws4[(k4 * 4 + 0) * 32 + cg];
        float4 wv1 = Ws4[(k4 * 4 + 1) * 32 + cg];
        float4 wv2 = Ws4[(k4 * 4 + 2) * 32 + cg];
        float4 wv3 = Ws4[(k4 * 4 + 3) * 32 + cg];
#pragma unroll
        for (int r = 0; r < 4; ++r) {
            float4 xv = x4[(row0 + r) * 32 + k4];   // broadcast within 32-thread row group
            FMA4(acc[r], xv.x, wv0);
            FMA4(acc[r], xv.y, wv1);
            FMA4(acc[r], xv.z, wv2);
            FMA4(acc[r], xv.w, wv3);
        }
    }
    float4* o4 = (float4*)h1;
#pragma unroll
    for (int r = 0; r < 4; ++r) o4[(row0 + r) * 32 + cg] = acc[r];

    // al epilogue: als/ald per row per head; 16-lane group reduce (head = cg>>4)
    float4 asv = ((const float4*)a_s)[cg];
    float4 adv = ((const float4*)a_d)[cg];
#pragma unroll
    for (int r = 0; r < 4; ++r) {
        float ps = acc[r].x * asv.x + acc[r].y * asv.y + acc[r].z * asv.z + acc[r].w * asv.w;
        float pd = acc[r].x * adv.x + acc[r].y * adv.y + acc[r].z * adv.z + acc[r].w * adv.w;
#pragma unroll
        for (int mm = 1; mm <= 8; mm <<= 1) { ps += __shfl_xor(ps, mm); pd += __shfl_xor(pd, mm); }
        if ((lane & 15) == 0) {
            int h = cg >> 4;
            als[(row0 + r) * 2 + h] = ps;
            ald[(row0 + r) * 2 + h] = pd;
        }
    }
}

// ---------------- GEMM2: h2 = helu @ W2   [NN,128] x [128,40] ----------------
__global__ __launch_bounds__(256) void gemm2_kernel(const float* __restrict__ xin,
                                                    const float* __restrict__ W,
                                                    float* __restrict__ h2) {
    __shared__ float Ws[128 * 40];             // 20 KiB
    const float4* W4 = (const float4*)W;
    float4* Ws4 = (float4*)Ws;
    for (int i = threadIdx.x; i < 128 * 40 / 4; i += 256) Ws4[i] = W4[i];
    __syncthreads();

    int t = threadIdx.x;
    if (t >= 250) return;                       // 10 col groups x 25 row groups
    int cg = t % 10;
    int rg = t / 10;
    int row0 = blockIdx.x * 100 + rg * 4;       // 1000 blocks
    const float4* x4 = (const float4*)xin;

    float4 acc[4];
    acc[0] = acc[1] = acc[2] = acc[3] = make_float4(0.f, 0.f, 0.f, 0.f);

    for (int k4 = 0; k4 < 32; ++k4) {
        float4 wv0 = Ws4[(k4 * 4 + 0) * 10 + cg];
        float4 wv1 = Ws4[(k4 * 4 + 1) * 10 + cg];
        float4 wv2 = Ws4[(k4 * 4 + 2) * 10 + cg];
        float4 wv3 = Ws4[(k4 * 4 + 3) * 10 + cg];
#pragma unroll
        for (int r = 0; r < 4; ++r) {
            float4 xv = x4[(row0 + r) * 32 + k4];
            FMA4(acc[r], xv.x, wv0);
            FMA4(acc[r], xv.y, wv1);
            FMA4(acc[r], xv.z, wv2);
            FMA4(acc[r], xv.w, wv3);
        }
    }
    float4* o4 = (float4*)h2;                   // 40 floats/row = 10 float4
#pragma unroll
    for (int r = 0; r < 4; ++r) o4[(row0 + r) * 10 + cg] = acc[r];
}

// ---------------- al2: per-node attention scalars for layer 2 ----------------
__global__ __launch_bounds__(256) void al2_kernel(const float* __restrict__ h2,
                                                  const float* __restrict__ a_s,
                                                  const float* __restrict__ a_d,
                                                  float* __restrict__ als,
                                                  float* __restrict__ ald) {
    int lane = threadIdx.x & 63;
    int row = blockIdx.x * 4 + (threadIdx.x >> 6);
    float v  = (lane < NC) ? h2[row * 40 + lane] : 0.f;
    float as_ = (lane < NC) ? a_s[lane] : 0.f;
    float ad_ = (lane < NC) ? a_d[lane] : 0.f;
    float s = v * as_, d = v * ad_;
    for (int m = 32; m; m >>= 1) { s += __shfl_xor(s, m); d += __shfl_xor(d, m); }
    if (lane == 0) { als[row] = s; ald[row] = d; }
}

// ---------------- CSR build (by dst) ----------------
__global__ __launch_bounds__(256) void count_kernel(const int* __restrict__ ei,
                                                    int* __restrict__ deg) {
    int j = blockIdx.x * 256 + threadIdx.x;
    if (j >= E2) return;
    int d = (j < NE) ? ei[NE + j] : (j - NE);
    atomicAdd(&deg[d], 1);
}

__global__ __launch_bounds__(256) void scan1_kernel(const int* __restrict__ deg,
                                                    int* __restrict__ offs,
                                                    int* __restrict__ bsum) {
    __shared__ int sh[256];
    int base = blockIdx.x * 1024 + threadIdx.x * 4;
    int v[4];
#pragma unroll
    for (int u = 0; u < 4; ++u) { int idx = base + u; v[u] = (idx < NN) ? deg[idx] : 0; }
    int t0 = v[0] + v[1] + v[2] + v[3];
    sh[threadIdx.x] = t0;
    __syncthreads();
    for (int off = 1; off < 256; off <<= 1) {
        int a = sh[threadIdx.x];
        int b = (threadIdx.x >= off) ? sh[threadIdx.x - off] : 0;
        __syncthreads();
        sh[threadIdx.x] = a + b;
        __syncthreads();
    }
    int excl = sh[threadIdx.x] - t0;
    if (threadIdx.x == 255) bsum[blockIdx.x] = sh[255];
    int run = excl;
#pragma unroll
    for (int u = 0; u < 4; ++u) { int idx = base + u; if (idx < NN) offs[idx] = run; run += v[u]; }
}

__global__ void scan2_kernel(int* __restrict__ bsum, int* __restrict__ offs) {
    __shared__ int sh[128];
    int i = threadIdx.x;
    int v = (i < 98) ? bsum[i] : 0;
    sh[i] = v;
    __syncthreads();
    for (int off = 1; off < 128; off <<= 1) {
        int a = sh[i];
        int b = (i >= off) ? sh[i - off] : 0;
        __syncthreads();
        sh[i] = a + b;
        __syncthreads();
    }
    if (i < 98) bsum[i] = sh[i] - v;            // exclusive
    if (i == 127) offs[NN] = sh[127];           // total = E2
}

__global__ __launch_bounds__(256) void scan3_kernel(int* __restrict__ offs,
                                                    const int* __restrict__ bsum) {
    int i = blockIdx.x * 256 + threadIdx.x;
    if (i < NN) offs[i] += bsum[i >> 10];
}

__global__ __launch_bounds__(256) void place_kernel(const int* __restrict__ ei,
                                                    const int* __restrict__ offs,
                                                    int* __restrict__ cur,
                                                    int* __restrict__ csr) {
    int j = blockIdx.x * 256 + threadIdx.x;
    if (j >= E2) return;
    int s, d;
    if (j < NE) { s = ei[j]; d = ei[NE + j]; } else { s = d = j - NE; }
    int p = offs[d] + atomicAdd(&cur[d], 1);
    csr[p] = s;
}

// ---------------- Aggregation layer 1 (+bias +ELU) ----------------
// One wave per dst node. Pass A: max. Pass B: w=exp(e-m) -> LDS + denom.
// Pass C: paired-edge float4 gather (2 edges/iter), 1/denom applied at end.
__global__ __launch_bounds__(256) void agg1_kernel(const int* __restrict__ offs,
                                                   const int* __restrict__ csr,
                                                   const float* __restrict__ als,
                                                   const float* __restrict__ ald,
                                                   const float* __restrict__ h1,
                                                   const float* __restrict__ b,
                                                   float* __restrict__ helu) {
    __shared__ float wsh[4][2 * MAXD];          // 4 KiB
    int lane = threadIdx.x & 63;
    int nw = threadIdx.x >> 6;
    int node = blockIdx.x * 4 + nw;
    int start = offs[node], end = offs[node + 1];
    const float2* als2 = (const float2*)als;
    float2 adv = ((const float2*)ald)[node];
    float* wn = wsh[nw];

    float m0 = -1e30f, m1 = -1e30f;
    for (int j = start + lane; j < end; j += 64) {
        float2 a = als2[csr[j]];
        float e0 = a.x + adv.x; e0 = e0 > 0.f ? e0 : NEG * e0;
        float e1 = a.y + adv.y; e1 = e1 > 0.f ? e1 : NEG * e1;
        m0 = fmaxf(m0, e0); m1 = fmaxf(m1, e1);
    }
    for (int mm = 32; mm; mm >>= 1) { m0 = fmaxf(m0, __shfl_xor(m0, mm)); m1 = fmaxf(m1, __shfl_xor(m1, mm)); }

    float s0 = 0.f, s1 = 0.f;
    for (int j = start + lane; j < end; j += 64) {
        int idx = j - start;
        float2 a = als2[csr[j]];
        float e0 = a.x + adv.x; e0 = e0 > 0.f ? e0 : NEG * e0;
        float e1 = a.y + adv.y; e1 = e1 > 0.f ? e1 : NEG * e1;
        float w0 = expf(e0 - m0), w1 = expf(e1 - m1);
        s0 += w0; s1 += w1;
        if (idx < MAXD) ((float2*)wn)[idx] = make_float2(w0, w1);
    }
    for (int mm = 32; mm; mm >>= 1) { s0 += __shfl_xor(s0, mm); s1 += __shfl_xor(s1, mm); }
    float inv0 = 1.f / (s0 + 1e-16f), inv1 = 1.f / (s1 + 1e-16f);

    int half = lane >> 5, l5 = lane & 31, hh = l5 >> 4;
    const float4* h14 = (const float4*)h1;
    float4 acc = make_float4(0.f, 0.f, 0.f, 0.f);
    for (int j2 = start; j2 < end; j2 += 2) {
        int j = j2 + half;
        if (j < end) {
            int s = csr[j];                     // uniform per half-wave
            int idx = j - start;
            float w;
            if (idx < MAXD) w = wn[idx * 2 + hh];
            else {                               // ultra-rare overflow path
                float e = als[s * 2 + hh] + (hh ? adv.y : adv.x);
                e = e > 0.f ? e : NEG * e;
                w = expf(e - (hh ? m1 : m0));
            }
            float4 hv = h14[s * 32 + l5];        // 512B per half-wave, contiguous
            acc.x = fmaf(w, hv.x, acc.x); acc.y = fmaf(w, hv.y, acc.y);
            acc.z = fmaf(w, hv.z, acc.z); acc.w = fmaf(w, hv.w, acc.w);
        }
    }
    acc.x += __shfl_xor(acc.x, 32); acc.y += __shfl_xor(acc.y, 32);
    acc.z += __shfl_xor(acc.z, 32); acc.w += __shfl_xor(acc.w, 32);
    if (lane < 32) {
        float inv = hh ? inv1 : inv0;
        float4 bb = ((const float4*)b)[l5];
        float4 o;
        o.x = fmaf(acc.x, inv, bb.x); o.y = fmaf(acc.y, inv, bb.y);
        o.z = fmaf(acc.z, inv, bb.z); o.w = fmaf(acc.w, inv, bb.w);
        o.x = o.x > 0.f ? o.x : expm1f(o.x); o.y = o.y > 0.f ? o.y : expm1f(o.y);
        o.z = o.z > 0.f ? o.z : expm1f(o.z); o.w = o.w > 0.f ? o.w : expm1f(o.w);
        ((float4*)helu)[node * 32 + l5] = o;
    }
}

// ---------------- Aggregation layer 2 (+bias) fused log_softmax ----------------
// 4 edges/iter (16-lane groups), 10 active float4 lanes per group.
__global__ __launch_bounds__(256) void agg2_kernel(const int* __restrict__ offs,
                                                   const int* __restrict__ csr,
                                                   const float* __restrict__ als,
                                                   const float* __restrict__ ald,
                                                   const float* __restrict__ h2,
                                                   const float* __restrict__ b,
                                                   float* __restrict__ out) {
    __shared__ float wsh[4][MAXD];              // 2 KiB
    int lane = threadIdx.x & 63;
    int nw = threadIdx.x >> 6;
    int node = blockIdx.x * 4 + nw;
    int start = offs[node], end = offs[node + 1];
    float ad = ald[node];
    float* wn = wsh[nw];

    float m = -1e30f;
    for (int j = start + lane; j < end; j += 64) {
        float e = als[csr[j]] + ad; e = e > 0.f ? e : NEG * e;
        m = fmaxf(m, e);
    }
    for (int mm = 32; mm; mm >>= 1) m = fmaxf(m, __shfl_xor(m, mm));

    float ssum = 0.f;
    for (int j = start + lane; j < end; j += 64) {
        int idx = j - start;
        float e = als[csr[j]] + ad; e = e > 0.f ? e : NEG * e;
        float w = expf(e - m);
        ssum += w;
        if (idx < MAXD) wn[idx] = w;
    }
    for (int mm = 32; mm; mm >>= 1) ssum += __shfl_xor(ssum, mm);
    float inv = 1.f / (ssum + 1e-16f);

    int q = lane >> 4, l4 = lane & 15;
    const float4* h24 = (const float4*)h2;
    float4 acc = make_float4(0.f, 0.f, 0.f, 0.f);
    for (int j2 = start; j2 < end; j2 += 4) {
        int j = j2 + q;
        if (j < end) {
            int s = csr[j];                     // uniform per 16-lane group
            int idx = j - start;
            float w;
            if (idx < MAXD) w = wn[idx];
            else { float e = als[s] + ad; e = e > 0.f ? e : NEG * e; w = expf(e - m); }
            if (l4 < 10) {
                float4 hv = h24[s * 10 + l4];
                acc.x = fmaf(w, hv.x, acc.x); acc.y = fmaf(w, hv.y, acc.y);
                acc.z = fmaf(w, hv.z, acc.z); acc.w = fmaf(w, hv.w, acc.w);
            }
        }
    }
    acc.x += __shfl_xor(acc.x, 16); acc.y += __shfl_xor(acc.y, 16);
    acc.z += __shfl_xor(acc.z, 16); acc.w += __shfl_xor(acc.w, 16);
    acc.x += __shfl_xor(acc.x, 32); acc.y += __shfl_xor(acc.y, 32);
    acc.z += __shfl_xor(acc.z, 32); acc.w += __shfl_xor(acc.w, 32);

    if (lane < 16) {
        float4 o = make_float4(-1e30f, -1e30f, -1e30f, -1e30f);
        if (l4 < 10) {
            float4 bb = ((const float4*)b)[l4];
            o.x = fmaf(acc.x, inv, bb.x); o.y = fmaf(acc.y, inv, bb.y);
            o.z = fmaf(acc.z, inv, bb.z); o.w = fmaf(acc.w, inv, bb.w);
        }
        // log_softmax over 40 classes, within 16-lane group
        float mx = fmaxf(fmaxf(o.x, o.y), fmaxf(o.z, o.w));
#pragma unroll
        for (int mm = 1; mm <= 8; mm <<= 1) mx = fmaxf(mx, __shfl_xor(mx, mm));
        float es = (expf(o.x - mx) + expf(o.y - mx)) + (expf(o.z - mx) + expf(o.w - mx));
#pragma unroll
        for (int mm = 1; mm <= 8; mm <<= 1) es += __shfl_xor(es, mm);
        float lse = mx + logf(es);
        if (l4 < 10) {
            float4 r;
            r.x = o.x - lse; r.y = o.y - lse; r.z = o.z - lse; r.w = o.w - lse;
            ((float4*)out)[node * 10 + l4] = r;
        }
    }
}

// ---------------- launch ----------------
extern "C" void kernel_launch(void* const* d_in, const int* in_sizes, int n_in,
                              void* d_out, int out_size, void* d_ws, size_t ws_size,
                              hipStream_t stream) {
    const float* x   = (const float*)d_in[0];
    const int*   ei  = (const int*)  d_in[1];
    const float* W1  = (const float*)d_in[2];
    const float* as1 = (const float*)d_in[3];
    const float* ad1 = (const float*)d_in[4];
    const float* b1  = (const float*)d_in[5];
    const float* W2  = (const float*)d_in[6];
    const float* as2 = (const float*)d_in[7];
    const float* ad2 = (const float*)d_in[8];
    const float* b2  = (const float*)d_in[9];
    float* out = (float*)d_out;

    // workspace carve-up
    char* p = (char*)d_ws;
    auto alloc = [&](size_t bytes) { void* r = (void*)p; p += (bytes + 255) & ~size_t(255); return r; };
    float* h1   = (float*)alloc(sizeof(float) * NN * 128);
    float* helu = (float*)alloc(sizeof(float) * NN * 128);
    float* h2   = (float*)alloc(sizeof(float) * NN * 40);
    float* als1 = (float*)alloc(sizeof(float) * NN * 2);
    float* ald1 = (float*)alloc(sizeof(float) * NN * 2);
    float* als2 = (float*)alloc(sizeof(float) * NN);
    float* ald2 = (float*)alloc(sizeof(float) * NN);
    int*   deg  = (int*)  alloc(sizeof(int) * NN);
    int*   offs = (int*)  alloc(sizeof(int) * (NN + 1));
    int*   bsum = (int*)  alloc(sizeof(int) * 128);
    int*   csr  = (int*)  alloc(sizeof(int) * E2);

    // CSR build (dst-sorted adjacency)
    hipMemsetAsync(deg, 0, sizeof(int) * NN, stream);
    count_kernel<<<(E2 + 255) / 256, 256, 0, stream>>>(ei, deg);
    scan1_kernel<<<98, 256, 0, stream>>>(deg, offs, bsum);
    scan2_kernel<<<1, 128, 0, stream>>>(bsum, offs);
    scan3_kernel<<<(NN + 255) / 256, 256, 0, stream>>>(offs, bsum);
    hipMemsetAsync(deg, 0, sizeof(int) * NN, stream);   // reuse as cursor
    place_kernel<<<(E2 + 255) / 256, 256, 0, stream>>>(ei, offs, deg, csr);

    // Layer 1
    gemm1_kernel<<<3125, 256, 0, stream>>>(x, W1, as1, ad1, h1, als1, ald1);
    agg1_kernel<<<25000, 256, 0, stream>>>(offs, csr, als1, ald1, h1, b1, helu);

    // Layer 2
    gemm2_kernel<<<1000, 256, 0, stream>>>(helu, W2, h2);
    al2_kernel<<<25000, 256, 0, stream>>>(h2, as2, ad2, als2, ald2);
    agg2_kernel<<<25000, 256, 0, stream>>>(offs, csr, als2, ald2, h2, b2, out);
}

// Round 4
// 606.027 us; speedup vs baseline: 1.3818x; 1.0616x over previous
//
#include <hip/hip_runtime.h>
#include <math.h>

// Problem constants (fixed by the reference)
#define NN   100000           // nodes
#define NE   1600000          // edges (before self-loops)
#define E2   (NE + NN)        // edges incl. self-loops = 1,700,000
#define NC   40
#define NEG  0.2f
#define MAXD 128              // per-node LDS edge buffer (deg ~ Poisson(16)+1; P(>128) ~ 1e-60)

// NOTE: macro parameter names must not collide with .x/.y/.z/.w member tokens.
#define FMA4(acc_, s_, w_) { (acc_).x = fmaf((s_),(w_).x,(acc_).x); (acc_).y = fmaf((s_),(w_).y,(acc_).y); \
                             (acc_).z = fmaf((s_),(w_).z,(acc_).z); (acc_).w = fmaf((s_),(w_).w,(acc_).w); }

// ---------------- GEMM1: h1 = x @ W1  [NN,128]x[128,128], fused al1 epilogue ----------------
__global__ __launch_bounds__(256) void gemm1_kernel(const float* __restrict__ x,
                                                    const float* __restrict__ W,
                                                    const float* __restrict__ a_s,
                                                    const float* __restrict__ a_d,
                                                    float* __restrict__ h1,
                                                    float* __restrict__ als,
                                                    float* __restrict__ ald) {
    __shared__ float Ws[128 * 128];            // 64 KiB
    const float4* W4 = (const float4*)W;
    float4* Ws4 = (float4*)Ws;
    for (int i = threadIdx.x; i < 128 * 128 / 4; i += 256) Ws4[i] = W4[i];
    __syncthreads();

    int cg = threadIdx.x & 31;                 // cols 4cg..4cg+3
    int rg = threadIdx.x >> 5;                 // 8 row groups x 4 rows
    int lane = threadIdx.x & 63;
    int row0 = blockIdx.x * 32 + rg * 4;       // 3125 blocks
    const float4* x4 = (const float4*)x;

    float4 acc[4];
    acc[0] = acc[1] = acc[2] = acc[3] = make_float4(0.f, 0.f, 0.f, 0.f);

    for (int k4 = 0; k4 < 32; ++k4) {
        float4 wv0 = Ws4[(k4 * 4 + 0) * 32 + cg];
        float4 wv1 = Ws4[(k4 * 4 + 1) * 32 + cg];
        float4 wv2 = Ws4[(k4 * 4 + 2) * 32 + cg];
        float4 wv3 = Ws4[(k4 * 4 + 3) * 32 + cg];
#pragma unroll
        for (int r = 0; r < 4; ++r) {
            float4 xv = x4[(row0 + r) * 32 + k4];   // broadcast within 32-thread row group
            FMA4(acc[r], xv.x, wv0);
            FMA4(acc[r], xv.y, wv1);
            FMA4(acc[r], xv.z, wv2);
            FMA4(acc[r], xv.w, wv3);
        }
    }
    float4* o4 = (float4*)h1;
#pragma unroll
    for (int r = 0; r < 4; ++r) o4[(row0 + r) * 32 + cg] = acc[r];

    // al epilogue: als/ald per row per head; 16-lane group reduce (head = cg>>4)
    float4 asv = ((const float4*)a_s)[cg];
    float4 adv = ((const float4*)a_d)[cg];
#pragma unroll
    for (int r = 0; r < 4; ++r) {
        float ps = acc[r].x * asv.x + acc[r].y * asv.y + acc[r].z * asv.z + acc[r].w * asv.w;
        float pd = acc[r].x * adv.x + acc[r].y * adv.y + acc[r].z * adv.z + acc[r].w * adv.w;
#pragma unroll
        for (int mm = 1; mm <= 8; mm <<= 1) { ps += __shfl_xor(ps, mm); pd += __shfl_xor(pd, mm); }
        if ((lane & 15) == 0) {
            int h = cg >> 4;
            als[(row0 + r) * 2 + h] = ps;
            ald[(row0 + r) * 2 + h] = pd;
        }
    }
}

// ---------------- GEMM2: h2 = helu @ W2   [NN,128] x [128,40] ----------------
__global__ __launch_bounds__(256) void gemm2_kernel(const float* __restrict__ xin,
                                                    const float* __restrict__ W,
                                                    float* __restrict__ h2) {
    __shared__ float Ws[128 * 40];             // 20 KiB
    const float4* W4 = (const float4*)W;
    float4* Ws4 = (float4*)Ws;
    for (int i = threadIdx.x; i < 128 * 40 / 4; i += 256) Ws4[i] = W4[i];
    __syncthreads();

    int t = threadIdx.x;
    if (t >= 250) return;                       // 10 col groups x 25 row groups
    int cg = t % 10;
    int rg = t / 10;
    int row0 = blockIdx.x * 100 + rg * 4;       // 1000 blocks
    const float4* x4 = (const float4*)xin;

    float4 acc[4];
    acc[0] = acc[1] = acc[2] = acc[3] = make_float4(0.f, 0.f, 0.f, 0.f);

    for (int k4 = 0; k4 < 32; ++k4) {
        float4 wv0 = Ws4[(k4 * 4 + 0) * 10 + cg];
        float4 wv1 = Ws4[(k4 * 4 + 1) * 10 + cg];
        float4 wv2 = Ws4[(k4 * 4 + 2) * 10 + cg];
        float4 wv3 = Ws4[(k4 * 4 + 3) * 10 + cg];
#pragma unroll
        for (int r = 0; r < 4; ++r) {
            float4 xv = x4[(row0 + r) * 32 + k4];
            FMA4(acc[r], xv.x, wv0);
            FMA4(acc[r], xv.y, wv1);
            FMA4(acc[r], xv.z, wv2);
            FMA4(acc[r], xv.w, wv3);
        }
    }
    float4* o4 = (float4*)h2;                   // 40 floats/row = 10 float4
#pragma unroll
    for (int r = 0; r < 4; ++r) o4[(row0 + r) * 10 + cg] = acc[r];
}

// ---------------- cvec: c_s2 = W2 @ a_s2, c_d2 = W2 @ a_d2  (128 threads) ----------------
__global__ void cvec_kernel(const float* __restrict__ W2,
                            const float* __restrict__ a_s2,
                            const float* __restrict__ a_d2,
                            float* __restrict__ cs2,
                            float* __restrict__ cd2) {
    int k = threadIdx.x;                        // 0..127
    float ss = 0.f, dd = 0.f;
    for (int c = 0; c < NC; ++c) {
        float wv = W2[k * NC + c];
        ss = fmaf(wv, a_s2[c], ss);
        dd = fmaf(wv, a_d2[c], dd);
    }
    cs2[k] = ss;
    cd2[k] = dd;
}

// ---------------- CSR build (by dst) ----------------
__global__ __launch_bounds__(256) void count_kernel(const int* __restrict__ ei,
                                                    int* __restrict__ deg) {
    int j = blockIdx.x * 256 + threadIdx.x;
    if (j >= E2) return;
    int d = (j < NE) ? ei[NE + j] : (j - NE);
    atomicAdd(&deg[d], 1);
}

__global__ __launch_bounds__(256) void scan1_kernel(const int* __restrict__ deg,
                                                    int* __restrict__ offs,
                                                    int* __restrict__ bsum) {
    __shared__ int sh[256];
    int base = blockIdx.x * 1024 + threadIdx.x * 4;
    int v[4];
#pragma unroll
    for (int u = 0; u < 4; ++u) { int idx = base + u; v[u] = (idx < NN) ? deg[idx] : 0; }
    int t0 = v[0] + v[1] + v[2] + v[3];
    sh[threadIdx.x] = t0;
    __syncthreads();
    for (int off = 1; off < 256; off <<= 1) {
        int a = sh[threadIdx.x];
        int b = (threadIdx.x >= off) ? sh[threadIdx.x - off] : 0;
        __syncthreads();
        sh[threadIdx.x] = a + b;
        __syncthreads();
    }
    int excl = sh[threadIdx.x] - t0;
    if (threadIdx.x == 255) bsum[blockIdx.x] = sh[255];
    int run = excl;
#pragma unroll
    for (int u = 0; u < 4; ++u) { int idx = base + u; if (idx < NN) offs[idx] = run; run += v[u]; }
}

__global__ void scan2_kernel(int* __restrict__ bsum, int* __restrict__ offs) {
    __shared__ int sh[128];
    int i = threadIdx.x;
    int v = (i < 98) ? bsum[i] : 0;
    sh[i] = v;
    __syncthreads();
    for (int off = 1; off < 128; off <<= 1) {
        int a = sh[i];
        int b = (i >= off) ? sh[i - off] : 0;
        __syncthreads();
        sh[i] = a + b;
        __syncthreads();
    }
    if (i < 98) bsum[i] = sh[i] - v;            // exclusive
    if (i == 127) offs[NN] = sh[127];           // total = E2
}

__global__ __launch_bounds__(256) void scan3_kernel(int* __restrict__ offs,
                                                    const int* __restrict__ bsum) {
    int i = blockIdx.x * 256 + threadIdx.x;
    if (i < NN) offs[i] += bsum[i >> 10];
}

// cur pre-initialized to offs via d2d copy; atomicAdd gives final slot directly.
__global__ __launch_bounds__(256) void place_kernel(const int* __restrict__ ei,
                                                    int* __restrict__ cur,
                                                    int* __restrict__ csr) {
    int j = blockIdx.x * 256 + threadIdx.x;
    if (j >= E2) return;
    int s, d;
    if (j < NE) { s = ei[j]; d = ei[NE + j]; } else { s = d = j - NE; }
    int p = atomicAdd(&cur[d], 1);
    csr[p] = s;
}

// ---------------- Aggregation layer 1 (+bias +ELU, fused als2/ald2) ----------------
// One wave per dst node. Pass AB (lane-parallel): w=exp(leaky(e)) -> LDS (w,src), sum.
// Pass C: paired-edge float4 gather, 2x unrolled (4 edges/iter), 1/denom at end.
// No max-subtraction: e is bounded (inputs ~N(0,0.05^2) scale), softmax is shift-invariant.
__global__ __launch_bounds__(256) void agg1_kernel(const int* __restrict__ offs,
                                                   const int* __restrict__ csr,
                                                   const float* __restrict__ als,
                                                   const float* __restrict__ ald,
                                                   const float* __restrict__ h1,
                                                   const float* __restrict__ b,
                                                   const float* __restrict__ cs2,
                                                   const float* __restrict__ cd2,
                                                   float* __restrict__ helu,
                                                   float* __restrict__ als2,
                                                   float* __restrict__ ald2) {
    __shared__ float2 wsh[4][MAXD];             // 4 KiB
    __shared__ int    ssh[4][MAXD];             // 2 KiB
    int lane = threadIdx.x & 63;
    int nw = threadIdx.x >> 6;
    int node = blockIdx.x * 4 + nw;
    int start = offs[node], end = offs[node + 1];
    const float2* alsv = (const float2*)als;
    float2 adv = ((const float2*)ald)[node];

    // Pass AB: weights + denom; stash (w, src) in LDS
    float s0 = 0.f, s1 = 0.f;
    for (int j = start + lane; j < end; j += 64) {
        int idx = j - start;
        int s = csr[j];
        float2 a = alsv[s];
        float e0 = a.x + adv.x; e0 = e0 > 0.f ? e0 : NEG * e0;
        float e1 = a.y + adv.y; e1 = e1 > 0.f ? e1 : NEG * e1;
        float w0 = expf(e0), w1 = expf(e1);
        s0 += w0; s1 += w1;
        if (idx < MAXD) { wsh[nw][idx] = make_float2(w0, w1); ssh[nw][idx] = s; }
    }
    for (int mm = 32; mm; mm >>= 1) { s0 += __shfl_xor(s0, mm); s1 += __shfl_xor(s1, mm); }
    float inv0 = 1.f / (s0 + 1e-16f), inv1 = 1.f / (s1 + 1e-16f);

    // Pass C: gather. half-wave = one edge; 2x unroll = 4 edges/iter.
    int half = lane >> 5, l5 = lane & 31, hh = l5 >> 4;
    const float4* h14 = (const float4*)h1;
    float4 acc = make_float4(0.f, 0.f, 0.f, 0.f);
    int j2 = start;
    for (; j2 + 4 <= end; j2 += 4) {
        int jA = j2 + half, jB = j2 + 2 + half;
        int idxA = jA - start, idxB = jB - start;
        int sA, sB; float wA, wB;
        if (idxA < MAXD) { sA = ssh[nw][idxA]; float2 wv = wsh[nw][idxA]; wA = hh ? wv.y : wv.x; }
        else { sA = csr[jA]; float2 a = alsv[sA];
               float e = (hh ? a.y + adv.y : a.x + adv.x); e = e > 0.f ? e : NEG * e; wA = expf(e); }
        if (idxB < MAXD) { sB = ssh[nw][idxB]; float2 wv = wsh[nw][idxB]; wB = hh ? wv.y : wv.x; }
        else { sB = csr[jB]; float2 a = alsv[sB];
               float e = (hh ? a.y + adv.y : a.x + adv.x); e = e > 0.f ? e : NEG * e; wB = expf(e); }
        float4 hA = h14[sA * 32 + l5];          // two independent 512B gathers in flight
        float4 hB = h14[sB * 32 + l5];
        FMA4(acc, wA, hA);
        FMA4(acc, wB, hB);
    }
    for (; j2 < end; j2 += 2) {
        int j = j2 + half;
        if (j < end) {
            int idx = j - start;
            int s; float w;
            if (idx < MAXD) { s = ssh[nw][idx]; float2 wv = wsh[nw][idx]; w = hh ? wv.y : wv.x; }
            else { s = csr[j]; float2 a = alsv[s];
                   float e = (hh ? a.y + adv.y : a.x + adv.x); e = e > 0.f ? e : NEG * e; w = expf(e); }
            float4 hv = h14[s * 32 + l5];
            FMA4(acc, w, hv);
        }
    }
    acc.x += __shfl_xor(acc.x, 32); acc.y += __shfl_xor(acc.y, 32);
    acc.z += __shfl_xor(acc.z, 32); acc.w += __shfl_xor(acc.w, 32);
    if (lane < 32) {
        float inv = hh ? inv1 : inv0;
        float4 bb = ((const float4*)b)[l5];
        float4 o;
        o.x = fmaf(acc.x, inv, bb.x); o.y = fmaf(acc.y, inv, bb.y);
        o.z = fmaf(acc.z, inv, bb.z); o.w = fmaf(acc.w, inv, bb.w);
        o.x = o.x > 0.f ? o.x : expm1f(o.x); o.y = o.y > 0.f ? o.y : expm1f(o.y);
        o.z = o.z > 0.f ? o.z : expm1f(o.z); o.w = o.w > 0.f ? o.w : expm1f(o.w);
        ((float4*)helu)[node * 32 + l5] = o;

        // fused layer-2 attention scalars: als2 = helu . (W2 @ a_s2), ald2 likewise
        float4 cs = ((const float4*)cs2)[l5];
        float4 cd = ((const float4*)cd2)[l5];
        float ps = o.x * cs.x + o.y * cs.y + o.z * cs.z + o.w * cs.w;
        float pd = o.x * cd.x + o.y * cd.y + o.z * cd.z + o.w * cd.w;
#pragma unroll
        for (int mm = 1; mm <= 16; mm <<= 1) { ps += __shfl_xor(ps, mm); pd += __shfl_xor(pd, mm); }
        if (l5 == 0) { als2[node] = ps; ald2[node] = pd; }
    }
}

// ---------------- Aggregation layer 2 (+bias) fused log_softmax ----------------
// Pass AB as above; pass C: 16-lane group = one edge, 2x unroll = 8 edges/iter.
__global__ __launch_bounds__(256) void agg2_kernel(const int* __restrict__ offs,
                                                   const int* __restrict__ csr,
                                                   const float* __restrict__ als,
                                                   const float* __restrict__ ald,
                                                   const float* __restrict__ h2,
                                                   const float* __restrict__ b,
                                                   float* __restrict__ out) {
    __shared__ float wsh[4][MAXD];              // 2 KiB
    __shared__ int   ssh[4][MAXD];              // 2 KiB
    int lane = threadIdx.x & 63;
    int nw = threadIdx.x >> 6;
    int node = blockIdx.x * 4 + nw;
    int start = offs[node], end = offs[node + 1];
    float ad = ald[node];

    float ssum = 0.f;
    for (int j = start + lane; j < end; j += 64) {
        int idx = j - start;
        int s = csr[j];
        float e = als[s] + ad; e = e > 0.f ? e : NEG * e;
        float w = expf(e);
        ssum += w;
        if (idx < MAXD) { wsh[nw][idx] = w; ssh[nw][idx] = s; }
    }
    for (int mm = 32; mm; mm >>= 1) ssum += __shfl_xor(ssum, mm);
    float inv = 1.f / (ssum + 1e-16f);

    int q = lane >> 4, l4 = lane & 15;
    const float4* h24 = (const float4*)h2;
    float4 acc = make_float4(0.f, 0.f, 0.f, 0.f);
    int j2 = start;
    for (; j2 + 8 <= end; j2 += 8) {
        int jA = j2 + q, jB = j2 + 4 + q;
        int idxA = jA - start, idxB = jB - start;
        int sA, sB; float wA, wB;
        if (idxA < MAXD) { sA = ssh[nw][idxA]; wA = wsh[nw][idxA]; }
        else { sA = csr[jA]; float e = als[sA] + ad; e = e > 0.f ? e : NEG * e; wA = expf(e); }
        if (idxB < MAXD) { sB = ssh[nw][idxB]; wB = wsh[nw][idxB]; }
        else { sB = csr[jB]; float e = als[sB] + ad; e = e > 0.f ? e : NEG * e; wB = expf(e); }
        if (l4 < 10) {
            float4 hA = h24[sA * 10 + l4];
            float4 hB = h24[sB * 10 + l4];
            FMA4(acc, wA, hA);
            FMA4(acc, wB, hB);
        }
    }
    for (; j2 < end; j2 += 4) {
        int j = j2 + q;
        if (j < end) {
            int idx = j - start;
            int s; float w;
            if (idx < MAXD) { s = ssh[nw][idx]; w = wsh[nw][idx]; }
            else { s = csr[j]; float e = als[s] + ad; e = e > 0.f ? e : NEG * e; w = expf(e); }
            if (l4 < 10) {
                float4 hv = h24[s * 10 + l4];
                FMA4(acc, w, hv);
            }
        }
    }
    acc.x += __shfl_xor(acc.x, 16); acc.y += __shfl_xor(acc.y, 16);
    acc.z += __shfl_xor(acc.z, 16); acc.w += __shfl_xor(acc.w, 16);
    acc.x += __shfl_xor(acc.x, 32); acc.y += __shfl_xor(acc.y, 32);
    acc.z += __shfl_xor(acc.z, 32); acc.w += __shfl_xor(acc.w, 32);

    if (lane < 16) {
        float4 o = make_float4(-1e30f, -1e30f, -1e30f, -1e30f);
        if (l4 < 10) {
            float4 bb = ((const float4*)b)[l4];
            o.x = fmaf(acc.x, inv, bb.x); o.y = fmaf(acc.y, inv, bb.y);
            o.z = fmaf(acc.z, inv, bb.z); o.w = fmaf(acc.w, inv, bb.w);
        }
        // log_softmax over 40 classes, within 16-lane group
        float mx = fmaxf(fmaxf(o.x, o.y), fmaxf(o.z, o.w));
#pragma unroll
        for (int mm = 1; mm <= 8; mm <<= 1) mx = fmaxf(mx, __shfl_xor(mx, mm));
        float es = (expf(o.x - mx) + expf(o.y - mx)) + (expf(o.z - mx) + expf(o.w - mx));
#pragma unroll
        for (int mm = 1; mm <= 8; mm <<= 1) es += __shfl_xor(es, mm);
        float lse = mx + logf(es);
        if (l4 < 10) {
            float4 r;
            r.x = o.x - lse; r.y = o.y - lse; r.z = o.z - lse; r.w = o.w - lse;
            ((float4*)out)[node * 10 + l4] = r;
        }
    }
}

// ---------------- launch ----------------
extern "C" void kernel_launch(void* const* d_in, const int* in_sizes, int n_in,
                              void* d_out, int out_size, void* d_ws, size_t ws_size,
                              hipStream_t stream) {
    const float* x   = (const float*)d_in[0];
    const int*   ei  = (const int*)  d_in[1];
    const float* W1  = (const float*)d_in[2];
    const float* as1 = (const float*)d_in[3];
    const float* ad1 = (const float*)d_in[4];
    const float* b1  = (const float*)d_in[5];
    const float* W2  = (const float*)d_in[6];
    const float* as2 = (const float*)d_in[7];
    const float* ad2 = (const float*)d_in[8];
    const float* b2  = (const float*)d_in[9];
    float* out = (float*)d_out;

    // workspace carve-up
    char* p = (char*)d_ws;
    auto alloc = [&](size_t bytes) { void* r = (void*)p; p += (bytes + 255) & ~size_t(255); return r; };
    float* h1   = (float*)alloc(sizeof(float) * NN * 128);
    float* helu = (float*)alloc(sizeof(float) * NN * 128);
    float* h2   = (float*)alloc(sizeof(float) * NN * 40);
    float* als1 = (float*)alloc(sizeof(float) * NN * 2);
    float* ald1 = (float*)alloc(sizeof(float) * NN * 2);
    float* als2 = (float*)alloc(sizeof(float) * NN);
    float* ald2 = (float*)alloc(sizeof(float) * NN);
    float* cs2  = (float*)alloc(sizeof(float) * 128);
    float* cd2  = (float*)alloc(sizeof(float) * 128);
    int*   deg  = (int*)  alloc(sizeof(int) * NN);
    int*   cur  = (int*)  alloc(sizeof(int) * NN);
    int*   offs = (int*)  alloc(sizeof(int) * (NN + 1));
    int*   bsum = (int*)  alloc(sizeof(int) * 128);
    int*   csr  = (int*)  alloc(sizeof(int) * E2);

    // tiny precompute (independent)
    cvec_kernel<<<1, 128, 0, stream>>>(W2, as2, ad2, cs2, cd2);

    // CSR build (dst-sorted adjacency)
    hipMemsetAsync(deg, 0, sizeof(int) * NN, stream);
    count_kernel<<<(E2 + 255) / 256, 256, 0, stream>>>(ei, deg);
    scan1_kernel<<<98, 256, 0, stream>>>(deg, offs, bsum);
    scan2_kernel<<<1, 128, 0, stream>>>(bsum, offs);
    scan3_kernel<<<(NN + 255) / 256, 256, 0, stream>>>(offs, bsum);
    hipMemcpyAsync(cur, offs, sizeof(int) * NN, hipMemcpyDeviceToDevice, stream);
    place_kernel<<<(E2 + 255) / 256, 256, 0, stream>>>(ei, cur, csr);

    // Layer 1
    gemm1_kernel<<<3125, 256, 0, stream>>>(x, W1, as1, ad1, h1, als1, ald1);
    agg1_kernel<<<25000, 256, 0, stream>>>(offs, csr, als1, ald1, h1, b1, cs2, cd2,
                                           helu, als2, ald2);

    // Layer 2
    gemm2_kernel<<<1000, 256, 0, stream>>>(helu, W2, h2);
    agg2_kernel<<<25000, 256, 0, stream>>>(offs, csr, als2, ald2, h2, b2, out);
}

// Round 5
// 592.918 us; speedup vs baseline: 1.4123x; 1.0221x over previous
//
#include <hip/hip_runtime.h>
#include <math.h>

// Problem constants (fixed by the reference)
#define NN   100000           // nodes
#define NE   1600000          // edges (before self-loops)
#define E2   (NE + NN)        // edges incl. self-loops = 1,700,000
#define NC   40
#define NEG  0.2f
#define MAXD 128              // per-node LDS edge buffer (deg ~ Poisson(16)+1; P(>128) ~ 1e-60)

// NOTE: macro parameter names must not collide with .x/.y/.z/.w member tokens.
#define FMA4(acc_, s_, w_) { (acc_).x = fmaf((s_),(w_).x,(acc_).x); (acc_).y = fmaf((s_),(w_).y,(acc_).y); \
                             (acc_).z = fmaf((s_),(w_).z,(acc_).z); (acc_).w = fmaf((s_),(w_).w,(acc_).w); }

// ---------------- GEMM1: h1 = x @ W1  [NN,128]x[128,128], fused al1 epilogue ----------------
// W1 staged in TWO 32 KiB halves (K-split) -> LDS 32 KiB -> 5 blocks/CU (was 2 at 64 KiB).
__global__ __launch_bounds__(256) void gemm1_kernel(const float* __restrict__ x,
                                                    const float* __restrict__ W,
                                                    const float* __restrict__ a_s,
                                                    const float* __restrict__ a_d,
                                                    float* __restrict__ h1,
                                                    float* __restrict__ als,
                                                    float* __restrict__ ald) {
    __shared__ float Ws[64 * 128];             // 32 KiB (one K-half of W1)
    const float4* W4 = (const float4*)W;
    float4* Ws4 = (float4*)Ws;

    int cg = threadIdx.x & 31;                 // cols 4cg..4cg+3
    int rg = threadIdx.x >> 5;                 // 8 row groups x 4 rows
    int lane = threadIdx.x & 63;
    int row0 = blockIdx.x * 32 + rg * 4;       // 3125 blocks
    const float4* x4 = (const float4*)x;

    float4 acc[4];
    acc[0] = acc[1] = acc[2] = acc[3] = make_float4(0.f, 0.f, 0.f, 0.f);

    for (int ph = 0; ph < 2; ++ph) {
        if (ph) __syncthreads();               // previous half fully consumed
        for (int i = threadIdx.x; i < 2048; i += 256) Ws4[i] = W4[ph * 2048 + i];
        __syncthreads();
        for (int k4 = 0; k4 < 16; ++k4) {
            float4 wv0 = Ws4[(k4 * 4 + 0) * 32 + cg];
            float4 wv1 = Ws4[(k4 * 4 + 1) * 32 + cg];
            float4 wv2 = Ws4[(k4 * 4 + 2) * 32 + cg];
            float4 wv3 = Ws4[(k4 * 4 + 3) * 32 + cg];
#pragma unroll
            for (int r = 0; r < 4; ++r) {
                float4 xv = x4[(row0 + r) * 32 + ph * 16 + k4];  // broadcast within row group
                FMA4(acc[r], xv.x, wv0);
                FMA4(acc[r], xv.y, wv1);
                FMA4(acc[r], xv.z, wv2);
                FMA4(acc[r], xv.w, wv3);
            }
        }
    }
    float4* o4 = (float4*)h1;
#pragma unroll
    for (int r = 0; r < 4; ++r) o4[(row0 + r) * 32 + cg] = acc[r];

    // al epilogue: als/ald per row per head; 16-lane group reduce (head = cg>>4)
    float4 asv = ((const float4*)a_s)[cg];
    float4 adv = ((const float4*)a_d)[cg];
#pragma unroll
    for (int r = 0; r < 4; ++r) {
        float ps = acc[r].x * asv.x + acc[r].y * asv.y + acc[r].z * asv.z + acc[r].w * asv.w;
        float pd = acc[r].x * adv.x + acc[r].y * adv.y + acc[r].z * adv.z + acc[r].w * adv.w;
#pragma unroll
        for (int mm = 1; mm <= 8; mm <<= 1) { ps += __shfl_xor(ps, mm); pd += __shfl_xor(pd, mm); }
        if ((lane & 15) == 0) {
            int h = cg >> 4;
            als[(row0 + r) * 2 + h] = ps;
            ald[(row0 + r) * 2 + h] = pd;
        }
    }
}

// ---------------- GEMM2: h2 = helu @ W2   [NN,128] x [128,40] ----------------
__global__ __launch_bounds__(256) void gemm2_kernel(const float* __restrict__ xin,
                                                    const float* __restrict__ W,
                                                    float* __restrict__ h2) {
    __shared__ float Ws[128 * 40];             // 20 KiB
    const float4* W4 = (const float4*)W;
    float4* Ws4 = (float4*)Ws;
    for (int i = threadIdx.x; i < 128 * 40 / 4; i += 256) Ws4[i] = W4[i];
    __syncthreads();

    int t = threadIdx.x;
    if (t >= 250) return;                       // 10 col groups x 25 row groups
    int cg = t % 10;
    int rg = t / 10;
    int row0 = blockIdx.x * 100 + rg * 4;       // 1000 blocks
    const float4* x4 = (const float4*)xin;

    float4 acc[4];
    acc[0] = acc[1] = acc[2] = acc[3] = make_float4(0.f, 0.f, 0.f, 0.f);

    for (int k4 = 0; k4 < 32; ++k4) {
        float4 wv0 = Ws4[(k4 * 4 + 0) * 10 + cg];
        float4 wv1 = Ws4[(k4 * 4 + 1) * 10 + cg];
        float4 wv2 = Ws4[(k4 * 4 + 2) * 10 + cg];
        float4 wv3 = Ws4[(k4 * 4 + 3) * 10 + cg];
#pragma unroll
        for (int r = 0; r < 4; ++r) {
            float4 xv = x4[(row0 + r) * 32 + k4];
            FMA4(acc[r], xv.x, wv0);
            FMA4(acc[r], xv.y, wv1);
            FMA4(acc[r], xv.z, wv2);
            FMA4(acc[r], xv.w, wv3);
        }
    }
    float4* o4 = (float4*)h2;                   // 40 floats/row = 10 float4
#pragma unroll
    for (int r = 0; r < 4; ++r) o4[(row0 + r) * 10 + cg] = acc[r];
}

// ---------------- cvec: c_s2 = W2 @ a_s2, c_d2 = W2 @ a_d2  (128 threads) ----------------
__global__ void cvec_kernel(const float* __restrict__ W2,
                            const float* __restrict__ a_s2,
                            const float* __restrict__ a_d2,
                            float* __restrict__ cs2,
                            float* __restrict__ cd2) {
    int k = threadIdx.x;                        // 0..127
    float ss = 0.f, dd = 0.f;
    for (int c = 0; c < NC; ++c) {
        float wv = W2[k * NC + c];
        ss = fmaf(wv, a_s2[c], ss);
        dd = fmaf(wv, a_d2[c], dd);
    }
    cs2[k] = ss;
    cd2[k] = dd;
}

// ---------------- CSR build (by dst), 4 edges/thread ----------------
__global__ __launch_bounds__(256) void count_kernel(const int* __restrict__ ei,
                                                    int* __restrict__ deg) {
    int j0 = (blockIdx.x * 256 + threadIdx.x) * 4;
    if (j0 >= E2) return;
    if (j0 < NE) {                              // NE%4==0 -> branch uniform per thread
        int4 d4 = *(const int4*)&ei[NE + j0];
        atomicAdd(&deg[d4.x], 1); atomicAdd(&deg[d4.y], 1);
        atomicAdd(&deg[d4.z], 1); atomicAdd(&deg[d4.w], 1);
    } else {
        int bse = j0 - NE;
        atomicAdd(&deg[bse], 1); atomicAdd(&deg[bse + 1], 1);
        atomicAdd(&deg[bse + 2], 1); atomicAdd(&deg[bse + 3], 1);
    }
}

__global__ __launch_bounds__(256) void scan1_kernel(const int* __restrict__ deg,
                                                    int* __restrict__ offs,
                                                    int* __restrict__ bsum) {
    __shared__ int sh[256];
    int base = blockIdx.x * 1024 + threadIdx.x * 4;
    int v[4];
#pragma unroll
    for (int u = 0; u < 4; ++u) { int idx = base + u; v[u] = (idx < NN) ? deg[idx] : 0; }
    int t0 = v[0] + v[1] + v[2] + v[3];
    sh[threadIdx.x] = t0;
    __syncthreads();
    for (int off = 1; off < 256; off <<= 1) {
        int a = sh[threadIdx.x];
        int b = (threadIdx.x >= off) ? sh[threadIdx.x - off] : 0;
        __syncthreads();
        sh[threadIdx.x] = a + b;
        __syncthreads();
    }
    int excl = sh[threadIdx.x] - t0;
    if (threadIdx.x == 255) bsum[blockIdx.x] = sh[255];
    int run = excl;
#pragma unroll
    for (int u = 0; u < 4; ++u) { int idx = base + u; if (idx < NN) offs[idx] = run; run += v[u]; }
}

__global__ void scan2_kernel(int* __restrict__ bsum, int* __restrict__ offs) {
    __shared__ int sh[128];
    int i = threadIdx.x;
    int v = (i < 98) ? bsum[i] : 0;
    sh[i] = v;
    __syncthreads();
    for (int off = 1; off < 128; off <<= 1) {
        int a = sh[i];
        int b = (i >= off) ? sh[i - off] : 0;
        __syncthreads();
        sh[i] = a + b;
        __syncthreads();
    }
    if (i < 98) bsum[i] = sh[i] - v;            // exclusive
    if (i == 127) offs[NN] = sh[127];           // total = E2
}

__global__ __launch_bounds__(256) void scan3_kernel(int* __restrict__ offs,
                                                    const int* __restrict__ bsum) {
    int i = blockIdx.x * 256 + threadIdx.x;
    if (i < NN) offs[i] += bsum[i >> 10];
}

// cur pre-initialized to offs via d2d copy; atomicAdd gives final slot directly.
__global__ __launch_bounds__(256) void place_kernel(const int* __restrict__ ei,
                                                    int* __restrict__ cur,
                                                    int* __restrict__ csr) {
    int j0 = (blockIdx.x * 256 + threadIdx.x) * 4;
    if (j0 >= E2) return;
    if (j0 < NE) {
        int4 s4 = *(const int4*)&ei[j0];
        int4 d4 = *(const int4*)&ei[NE + j0];
        int p;
        p = atomicAdd(&cur[d4.x], 1); csr[p] = s4.x;
        p = atomicAdd(&cur[d4.y], 1); csr[p] = s4.y;
        p = atomicAdd(&cur[d4.z], 1); csr[p] = s4.z;
        p = atomicAdd(&cur[d4.w], 1); csr[p] = s4.w;
    } else {
        int bse = j0 - NE;
#pragma unroll
        for (int k = 0; k < 4; ++k) {
            int n = bse + k;
            int p = atomicAdd(&cur[n], 1); csr[p] = n;
        }
    }
}

// ---------------- Aggregation layer 1 (+bias +ELU, fused als2/ald2) ----------------
// One wave per dst node. Pass AB (lane-parallel): w=exp(leaky(e)) -> LDS (w,src), sum.
// Pass C: half-wave = one edge, 4x unrolled (8 edges/iter, 4 gathers in flight/lane).
// No max-subtraction: e is bounded (inputs ~N(0,0.05^2) scale), softmax is shift-invariant.
__global__ __launch_bounds__(256) void agg1_kernel(const int* __restrict__ offs,
                                                   const int* __restrict__ csr,
                                                   const float* __restrict__ als,
                                                   const float* __restrict__ ald,
                                                   const float* __restrict__ h1,
                                                   const float* __restrict__ b,
                                                   const float* __restrict__ cs2,
                                                   const float* __restrict__ cd2,
                                                   float* __restrict__ helu,
                                                   float* __restrict__ als2,
                                                   float* __restrict__ ald2) {
    __shared__ float wsh[4][2 * MAXD];          // 4 KiB
    __shared__ int   ssh[4][MAXD];              // 2 KiB
    int lane = threadIdx.x & 63;
    int nw = threadIdx.x >> 6;
    int node = blockIdx.x * 4 + nw;
    int start = offs[node], end = offs[node + 1];
    const float2* alsv = (const float2*)als;
    float2 adv = ((const float2*)ald)[node];
    float* wn = wsh[nw];
    int* sn = ssh[nw];

    // Pass AB: weights + denom; stash (w, src) in LDS
    float s0 = 0.f, s1 = 0.f;
    for (int j = start + lane; j < end; j += 64) {
        int idx = j - start;
        int s = csr[j];
        float2 a = alsv[s];
        float e0 = a.x + adv.x; e0 = e0 > 0.f ? e0 : NEG * e0;
        float e1 = a.y + adv.y; e1 = e1 > 0.f ? e1 : NEG * e1;
        float w0 = expf(e0), w1 = expf(e1);
        s0 += w0; s1 += w1;
        if (idx < MAXD) { wn[idx * 2] = w0; wn[idx * 2 + 1] = w1; sn[idx] = s; }
    }
    for (int mm = 32; mm; mm >>= 1) { s0 += __shfl_xor(s0, mm); s1 += __shfl_xor(s1, mm); }
    float inv0 = 1.f / (s0 + 1e-16f), inv1 = 1.f / (s1 + 1e-16f);

    // Pass C: gather. half-wave = one edge; 4x unroll = 8 edges/iter.
    int half = lane >> 5, l5 = lane & 31, hh = l5 >> 4;
    const float4* h14 = (const float4*)h1;
    float4 acc = make_float4(0.f, 0.f, 0.f, 0.f);
    int j2 = start;
#define AGG1_FETCH(jv_, sv_, wv_) { \
        int idx_ = (jv_) - start; \
        if (idx_ < MAXD) { sv_ = sn[idx_]; wv_ = wn[idx_ * 2 + hh]; } \
        else { sv_ = csr[jv_]; float2 a_ = alsv[sv_]; \
               float e_ = (hh ? a_.y + adv.y : a_.x + adv.x); e_ = e_ > 0.f ? e_ : NEG * e_; wv_ = expf(e_); } }
    for (; j2 + 8 <= end; j2 += 8) {
        int jA = j2 + half, jB = jA + 2, jC = jA + 4, jD = jA + 6;
        int sA, sB, sC, sD; float wA, wB, wC, wD;
        AGG1_FETCH(jA, sA, wA); AGG1_FETCH(jB, sB, wB);
        AGG1_FETCH(jC, sC, wC); AGG1_FETCH(jD, sD, wD);
        float4 hA = h14[sA * 32 + l5];          // 4 independent 512B gathers in flight
        float4 hB = h14[sB * 32 + l5];
        float4 hC = h14[sC * 32 + l5];
        float4 hD = h14[sD * 32 + l5];
        FMA4(acc, wA, hA);
        FMA4(acc, wB, hB);
        FMA4(acc, wC, hC);
        FMA4(acc, wD, hD);
    }
    for (; j2 < end; j2 += 2) {
        int j = j2 + half;
        if (j < end) {
            int s; float w;
            AGG1_FETCH(j, s, w);
            float4 hv = h14[s * 32 + l5];
            FMA4(acc, w, hv);
        }
    }
#undef AGG1_FETCH
    acc.x += __shfl_xor(acc.x, 32); acc.y += __shfl_xor(acc.y, 32);
    acc.z += __shfl_xor(acc.z, 32); acc.w += __shfl_xor(acc.w, 32);
    if (lane < 32) {
        float inv = hh ? inv1 : inv0;
        float4 bb = ((const float4*)b)[l5];
        float4 o;
        o.x = fmaf(acc.x, inv, bb.x); o.y = fmaf(acc.y, inv, bb.y);
        o.z = fmaf(acc.z, inv, bb.z); o.w = fmaf(acc.w, inv, bb.w);
        o.x = o.x > 0.f ? o.x : expm1f(o.x); o.y = o.y > 0.f ? o.y : expm1f(o.y);
        o.z = o.z > 0.f ? o.z : expm1f(o.z); o.w = o.w > 0.f ? o.w : expm1f(o.w);
        ((float4*)helu)[node * 32 + l5] = o;

        // fused layer-2 attention scalars: als2 = helu . (W2 @ a_s2), ald2 likewise
        float4 cs = ((const float4*)cs2)[l5];
        float4 cd = ((const float4*)cd2)[l5];
        float ps = o.x * cs.x + o.y * cs.y + o.z * cs.z + o.w * cs.w;
        float pd = o.x * cd.x + o.y * cd.y + o.z * cd.z + o.w * cd.w;
#pragma unroll
        for (int mm = 1; mm <= 16; mm <<= 1) { ps += __shfl_xor(ps, mm); pd += __shfl_xor(pd, mm); }
        if (l5 == 0) { als2[node] = ps; ald2[node] = pd; }
    }
}

// ---------------- Aggregation layer 2 (+bias) fused log_softmax ----------------
// Pass AB as above; pass C: 10-lane group = one edge (6 edges/wave, lanes 60-63 idle),
// 2x unroll = 12 gathers in flight; per-wave LDS buffer for cross-group reduction.
__global__ __launch_bounds__(256) void agg2_kernel(const int* __restrict__ offs,
                                                   const int* __restrict__ csr,
                                                   const float* __restrict__ als,
                                                   const float* __restrict__ ald,
                                                   const float* __restrict__ h2,
                                                   const float* __restrict__ b,
                                                   float* __restrict__ out) {
    __shared__ float  wsh[4][MAXD];             // 2 KiB
    __shared__ int    ssh[4][MAXD];             // 2 KiB
    __shared__ float4 red[4][6][10];            // 3.75 KiB
    int lane = threadIdx.x & 63;
    int nw = threadIdx.x >> 6;
    int node = blockIdx.x * 4 + nw;
    int start = offs[node], end = offs[node + 1];
    float ad = ald[node];
    float* wn = wsh[nw];
    int* sn = ssh[nw];

    float ssum = 0.f;
    for (int j = start + lane; j < end; j += 64) {
        int idx = j - start;
        int s = csr[j];
        float e = als[s] + ad; e = e > 0.f ? e : NEG * e;
        float w = expf(e);
        ssum += w;
        if (idx < MAXD) { wn[idx] = w; sn[idx] = s; }
    }
    for (int mm = 32; mm; mm >>= 1) ssum += __shfl_xor(ssum, mm);
    float inv = 1.f / (ssum + 1e-16f);

    int g = lane / 10, c = lane % 10;           // 6 groups of 10 lanes; 60..63 idle
    const float4* h24 = (const float4*)h2;
#define AGG2_FETCH(jv_, sv_, wv_) { \
        int idx_ = (jv_) - start; \
        if (idx_ < MAXD) { sv_ = sn[idx_]; wv_ = wn[idx_]; } \
        else { sv_ = csr[jv_]; float e_ = als[sv_] + ad; e_ = e_ > 0.f ? e_ : NEG * e_; wv_ = expf(e_); } }
    if (g < 6) {
        float4 acc = make_float4(0.f, 0.f, 0.f, 0.f);
        int j2 = start;
        for (; j2 + 12 <= end; j2 += 12) {
            int jA = j2 + g, jB = jA + 6;
            int sA, sB; float wA, wB;
            AGG2_FETCH(jA, sA, wA); AGG2_FETCH(jB, sB, wB);
            float4 hA = h24[sA * 10 + c];       // 2 independent 160B gathers in flight
            float4 hB = h24[sB * 10 + c];
            FMA4(acc, wA, hA);
            FMA4(acc, wB, hB);
        }
        for (; j2 < end; j2 += 6) {
            int j = j2 + g;
            if (j < end) {
                int s; float w;
                AGG2_FETCH(j, s, w);
                float4 hv = h24[s * 10 + c];
                FMA4(acc, w, hv);
            }
        }
        red[nw][g][c] = acc;                    // same-wave DS ordering; no barrier needed
    }
#undef AGG2_FETCH

    if (lane < 16) {
        bool act = lane < 10;
        float4 o = make_float4(-1e30f, -1e30f, -1e30f, -1e30f);
        if (act) {
            float4 tot = make_float4(0.f, 0.f, 0.f, 0.f);
#pragma unroll
            for (int k = 0; k < 6; ++k) {
                float4 r = red[nw][k][lane];
                tot.x += r.x; tot.y += r.y; tot.z += r.z; tot.w += r.w;
            }
            float4 bb = ((const float4*)b)[lane];
            o.x = fmaf(tot.x, inv, bb.x); o.y = fmaf(tot.y, inv, bb.y);
            o.z = fmaf(tot.z, inv, bb.z); o.w = fmaf(tot.w, inv, bb.w);
        }
        // log_softmax over 40 classes within lanes 0..15 (10 active, 6 neutral)
        float mx = fmaxf(fmaxf(o.x, o.y), fmaxf(o.z, o.w));
#pragma unroll
        for (int mm = 1; mm <= 8; mm <<= 1) mx = fmaxf(mx, __shfl_xor(mx, mm));
        float es = (expf(o.x - mx) + expf(o.y - mx)) + (expf(o.z - mx) + expf(o.w - mx));
#pragma unroll
        for (int mm = 1; mm <= 8; mm <<= 1) es += __shfl_xor(es, mm);
        float lse = mx + logf(es);
        if (act) {
            float4 r;
            r.x = o.x - lse; r.y = o.y - lse; r.z = o.z - lse; r.w = o.w - lse;
            ((float4*)out)[node * 10 + lane] = r;
        }
    }
}

// ---------------- launch ----------------
extern "C" void kernel_launch(void* const* d_in, const int* in_sizes, int n_in,
                              void* d_out, int out_size, void* d_ws, size_t ws_size,
                              hipStream_t stream) {
    const float* x   = (const float*)d_in[0];
    const int*   ei  = (const int*)  d_in[1];
    const float* W1  = (const float*)d_in[2];
    const float* as1 = (const float*)d_in[3];
    const float* ad1 = (const float*)d_in[4];
    const float* b1  = (const float*)d_in[5];
    const float* W2  = (const float*)d_in[6];
    const float* as2 = (const float*)d_in[7];
    const float* ad2 = (const float*)d_in[8];
    const float* b2  = (const float*)d_in[9];
    float* out = (float*)d_out;

    // workspace carve-up
    char* p = (char*)d_ws;
    auto alloc = [&](size_t bytes) { void* r = (void*)p; p += (bytes + 255) & ~size_t(255); return r; };
    float* h1   = (float*)alloc(sizeof(float) * NN * 128);
    float* helu = (float*)alloc(sizeof(float) * NN * 128);
    float* h2   = (float*)alloc(sizeof(float) * NN * 40);
    float* als1 = (float*)alloc(sizeof(float) * NN * 2);
    float* ald1 = (float*)alloc(sizeof(float) * NN * 2);
    float* als2 = (float*)alloc(sizeof(float) * NN);
    float* ald2 = (float*)alloc(sizeof(float) * NN);
    float* cs2  = (float*)alloc(sizeof(float) * 128);
    float* cd2  = (float*)alloc(sizeof(float) * 128);
    int*   deg  = (int*)  alloc(sizeof(int) * NN);
    int*   cur  = (int*)  alloc(sizeof(int) * NN);
    int*   offs = (int*)  alloc(sizeof(int) * (NN + 1));
    int*   bsum = (int*)  alloc(sizeof(int) * 128);
    int*   csr  = (int*)  alloc(sizeof(int) * E2);

    // tiny precompute (independent)
    cvec_kernel<<<1, 128, 0, stream>>>(W2, as2, ad2, cs2, cd2);

    // CSR build (dst-sorted adjacency)
    hipMemsetAsync(deg, 0, sizeof(int) * NN, stream);
    count_kernel<<<(E2 / 4 + 255) / 256, 256, 0, stream>>>(ei, deg);
    scan1_kernel<<<98, 256, 0, stream>>>(deg, offs, bsum);
    scan2_kernel<<<1, 128, 0, stream>>>(bsum, offs);
    scan3_kernel<<<(NN + 255) / 256, 256, 0, stream>>>(offs, bsum);
    hipMemcpyAsync(cur, offs, sizeof(int) * NN, hipMemcpyDeviceToDevice, stream);
    place_kernel<<<(E2 / 4 + 255) / 256, 256, 0, stream>>>(ei, cur, csr);

    // Layer 1
    gemm1_kernel<<<3125, 256, 0, stream>>>(x, W1, as1, ad1, h1, als1, ald1);
    agg1_kernel<<<25000, 256, 0, stream>>>(offs, csr, als1, ald1, h1, b1, cs2, cd2,
                                           helu, als2, ald2);

    // Layer 2
    gemm2_kernel<<<1000, 256, 0, stream>>>(helu, W2, h2);
    agg2_kernel<<<25000, 256, 0, stream>>>(offs, csr, als2, ald2, h2, b2, out);
}

// Round 6
// 532.925 us; speedup vs baseline: 1.5713x; 1.1126x over previous
//
#include <hip/hip_runtime.h>
#include <math.h>

// Problem constants (fixed by the reference)
#define NN   100000           // nodes
#define NE   1600000          // edges (before self-loops)
#define E2   (NE + NN)        // edges incl. self-loops = 1,700,000
#define NC   40
#define NEG  0.2f
#define MAXD 128              // per-node LDS edge buffer (deg ~ Poisson(16)+1; P(>128) ~ 1e-60)

// NOTE: macro parameter names must not collide with .x/.y/.z/.w member tokens.
#define FMA4(acc_, s_, w_) { (acc_).x = fmaf((s_),(w_).x,(acc_).x); (acc_).y = fmaf((s_),(w_).y,(acc_).y); \
                             (acc_).z = fmaf((s_),(w_).z,(acc_).z); (acc_).w = fmaf((s_),(w_).w,(acc_).w); }

// bf16 <-> f32 helpers (RNE pack; plain shift unpack)
__device__ inline float b2f(unsigned short u) {
    union { unsigned int i; float f; } v; v.i = (unsigned int)u << 16; return v.f;
}
__device__ inline float4 b2f4(ushort4 u) {
    return make_float4(b2f(u.x), b2f(u.y), b2f(u.z), b2f(u.w));
}
__device__ inline unsigned short f2b(float f) {
    union { float f; unsigned int i; } v; v.f = f;
    unsigned int r = (v.i + 0x7FFFu + ((v.i >> 16) & 1u)) >> 16;
    return (unsigned short)r;
}
__device__ inline ushort4 f2b4(float4 f) {
    return make_ushort4(f2b(f.x), f2b(f.y), f2b(f.z), f2b(f.w));
}

// ---------------- GEMM1: h1b = bf16(x @ W1)  [NN,128]x[128,128], fused al1 epilogue --------
// W1 staged in TWO 32 KiB halves (K-split) -> LDS 32 KiB. als/ald from fp32 accumulators.
__global__ __launch_bounds__(256) void gemm1_kernel(const float* __restrict__ x,
                                                    const float* __restrict__ W,
                                                    const float* __restrict__ a_s,
                                                    const float* __restrict__ a_d,
                                                    unsigned short* __restrict__ h1b,
                                                    float* __restrict__ als,
                                                    float* __restrict__ ald) {
    __shared__ float Ws[64 * 128];             // 32 KiB (one K-half of W1)
    const float4* W4 = (const float4*)W;
    float4* Ws4 = (float4*)Ws;

    int cg = threadIdx.x & 31;                 // cols 4cg..4cg+3
    int rg = threadIdx.x >> 5;                 // 8 row groups x 4 rows
    int lane = threadIdx.x & 63;
    int row0 = blockIdx.x * 32 + rg * 4;       // 3125 blocks
    const float4* x4 = (const float4*)x;

    float4 acc[4];
    acc[0] = acc[1] = acc[2] = acc[3] = make_float4(0.f, 0.f, 0.f, 0.f);

    for (int ph = 0; ph < 2; ++ph) {
        if (ph) __syncthreads();               // previous half fully consumed
        for (int i = threadIdx.x; i < 2048; i += 256) Ws4[i] = W4[ph * 2048 + i];
        __syncthreads();
        for (int k4 = 0; k4 < 16; ++k4) {
            float4 wv0 = Ws4[(k4 * 4 + 0) * 32 + cg];
            float4 wv1 = Ws4[(k4 * 4 + 1) * 32 + cg];
            float4 wv2 = Ws4[(k4 * 4 + 2) * 32 + cg];
            float4 wv3 = Ws4[(k4 * 4 + 3) * 32 + cg];
#pragma unroll
            for (int r = 0; r < 4; ++r) {
                float4 xv = x4[(row0 + r) * 32 + ph * 16 + k4];  // broadcast within row group
                FMA4(acc[r], xv.x, wv0);
                FMA4(acc[r], xv.y, wv1);
                FMA4(acc[r], xv.z, wv2);
                FMA4(acc[r], xv.w, wv3);
            }
        }
    }
    ushort4* o4 = (ushort4*)h1b;
#pragma unroll
    for (int r = 0; r < 4; ++r) o4[(row0 + r) * 32 + cg] = f2b4(acc[r]);

    // al epilogue: als/ald per row per head; 16-lane group reduce (head = cg>>4)
    float4 asv = ((const float4*)a_s)[cg];
    float4 adv = ((const float4*)a_d)[cg];
#pragma unroll
    for (int r = 0; r < 4; ++r) {
        float ps = acc[r].x * asv.x + acc[r].y * asv.y + acc[r].z * asv.z + acc[r].w * asv.w;
        float pd = acc[r].x * adv.x + acc[r].y * adv.y + acc[r].z * adv.z + acc[r].w * adv.w;
#pragma unroll
        for (int mm = 1; mm <= 8; mm <<= 1) { ps += __shfl_xor(ps, mm); pd += __shfl_xor(pd, mm); }
        if ((lane & 15) == 0) {
            int h = cg >> 4;
            als[(row0 + r) * 2 + h] = ps;
            ald[(row0 + r) * 2 + h] = pd;
        }
    }
}

// ---------------- GEMM2: h2b = bf16(heluB @ W2)   [NN,128] x [128,40] ----------------
__global__ __launch_bounds__(256) void gemm2_kernel(const unsigned short* __restrict__ heluB,
                                                    const float* __restrict__ W,
                                                    unsigned short* __restrict__ h2b) {
    __shared__ float Ws[128 * 40];             // 20 KiB
    const float4* W4 = (const float4*)W;
    float4* Ws4 = (float4*)Ws;
    for (int i = threadIdx.x; i < 128 * 40 / 4; i += 256) Ws4[i] = W4[i];
    __syncthreads();

    int t = threadIdx.x;
    if (t >= 250) return;                       // 10 col groups x 25 row groups
    int cg = t % 10;
    int rg = t / 10;
    int row0 = blockIdx.x * 100 + rg * 4;       // 1000 blocks
    const ushort4* x4 = (const ushort4*)heluB;

    float4 acc[4];
    acc[0] = acc[1] = acc[2] = acc[3] = make_float4(0.f, 0.f, 0.f, 0.f);

    for (int k4 = 0; k4 < 32; ++k4) {
        float4 wv0 = Ws4[(k4 * 4 + 0) * 10 + cg];
        float4 wv1 = Ws4[(k4 * 4 + 1) * 10 + cg];
        float4 wv2 = Ws4[(k4 * 4 + 2) * 10 + cg];
        float4 wv3 = Ws4[(k4 * 4 + 3) * 10 + cg];
#pragma unroll
        for (int r = 0; r < 4; ++r) {
            float4 xv = b2f4(x4[(row0 + r) * 32 + k4]);
            FMA4(acc[r], xv.x, wv0);
            FMA4(acc[r], xv.y, wv1);
            FMA4(acc[r], xv.z, wv2);
            FMA4(acc[r], xv.w, wv3);
        }
    }
    ushort4* o4 = (ushort4*)h2b;                // 40 bf16/row = 10 ushort4
#pragma unroll
    for (int r = 0; r < 4; ++r) o4[(row0 + r) * 10 + cg] = f2b4(acc[r]);
}

// ---------------- cvec: c_s2 = W2 @ a_s2, c_d2 = W2 @ a_d2  (128 threads) ----------------
__global__ void cvec_kernel(const float* __restrict__ W2,
                            const float* __restrict__ a_s2,
                            const float* __restrict__ a_d2,
                            float* __restrict__ cs2,
                            float* __restrict__ cd2) {
    int k = threadIdx.x;                        // 0..127
    float ss = 0.f, dd = 0.f;
    for (int c = 0; c < NC; ++c) {
        float wv = W2[k * NC + c];
        ss = fmaf(wv, a_s2[c], ss);
        dd = fmaf(wv, a_d2[c], dd);
    }
    cs2[k] = ss;
    cd2[k] = dd;
}

// ---------------- CSR build (by dst), 4 edges/thread ----------------
__global__ __launch_bounds__(256) void count_kernel(const int* __restrict__ ei,
                                                    int* __restrict__ deg) {
    int j0 = (blockIdx.x * 256 + threadIdx.x) * 4;
    if (j0 >= E2) return;
    if (j0 < NE) {                              // NE%4==0 -> branch uniform per thread
        int4 d4 = *(const int4*)&ei[NE + j0];
        atomicAdd(&deg[d4.x], 1); atomicAdd(&deg[d4.y], 1);
        atomicAdd(&deg[d4.z], 1); atomicAdd(&deg[d4.w], 1);
    } else {
        int bse = j0 - NE;
        atomicAdd(&deg[bse], 1); atomicAdd(&deg[bse + 1], 1);
        atomicAdd(&deg[bse + 2], 1); atomicAdd(&deg[bse + 3], 1);
    }
}

__global__ __launch_bounds__(256) void scan1_kernel(const int* __restrict__ deg,
                                                    int* __restrict__ offs,
                                                    int* __restrict__ bsum) {
    __shared__ int sh[256];
    int base = blockIdx.x * 1024 + threadIdx.x * 4;
    int v[4];
#pragma unroll
    for (int u = 0; u < 4; ++u) { int idx = base + u; v[u] = (idx < NN) ? deg[idx] : 0; }
    int t0 = v[0] + v[1] + v[2] + v[3];
    sh[threadIdx.x] = t0;
    __syncthreads();
    for (int off = 1; off < 256; off <<= 1) {
        int a = sh[threadIdx.x];
        int b = (threadIdx.x >= off) ? sh[threadIdx.x - off] : 0;
        __syncthreads();
        sh[threadIdx.x] = a + b;
        __syncthreads();
    }
    int excl = sh[threadIdx.x] - t0;
    if (threadIdx.x == 255) bsum[blockIdx.x] = sh[255];
    int run = excl;
#pragma unroll
    for (int u = 0; u < 4; ++u) { int idx = base + u; if (idx < NN) offs[idx] = run; run += v[u]; }
}

__global__ void scan2_kernel(int* __restrict__ bsum, int* __restrict__ offs) {
    __shared__ int sh[128];
    int i = threadIdx.x;
    int v = (i < 98) ? bsum[i] : 0;
    sh[i] = v;
    __syncthreads();
    for (int off = 1; off < 128; off <<= 1) {
        int a = sh[i];
        int b = (i >= off) ? sh[i - off] : 0;
        __syncthreads();
        sh[i] = a + b;
        __syncthreads();
    }
    if (i < 98) bsum[i] = sh[i] - v;            // exclusive
    if (i == 127) offs[NN] = sh[127];           // total = E2
}

__global__ __launch_bounds__(256) void scan3_kernel(int* __restrict__ offs,
                                                    const int* __restrict__ bsum) {
    int i = blockIdx.x * 256 + threadIdx.x;
    if (i < NN) offs[i] += bsum[i >> 10];
}

// cur pre-initialized to offs via d2d copy; atomicAdd gives final slot directly.
__global__ __launch_bounds__(256) void place_kernel(const int* __restrict__ ei,
                                                    int* __restrict__ cur,
                                                    int* __restrict__ csr) {
    int j0 = (blockIdx.x * 256 + threadIdx.x) * 4;
    if (j0 >= E2) return;
    if (j0 < NE) {
        int4 s4 = *(const int4*)&ei[j0];
        int4 d4 = *(const int4*)&ei[NE + j0];
        int p;
        p = atomicAdd(&cur[d4.x], 1); csr[p] = s4.x;
        p = atomicAdd(&cur[d4.y], 1); csr[p] = s4.y;
        p = atomicAdd(&cur[d4.z], 1); csr[p] = s4.z;
        p = atomicAdd(&cur[d4.w], 1); csr[p] = s4.w;
    } else {
        int bse = j0 - NE;
#pragma unroll
        for (int k = 0; k < 4; ++k) {
            int n = bse + k;
            int p = atomicAdd(&cur[n], 1); csr[p] = n;
        }
    }
}

// ---------------- Aggregation layer 1 (+bias +ELU, fused als2/ald2) ----------------
// One wave per dst node. Pass AB (lane-parallel): w=exp(leaky(e)) -> LDS (w,src), sum.
// Pass C: half-wave = one edge (256B bf16 row), 4x unrolled (8 edges/iter).
// No max-subtraction: e is bounded, softmax is shift-invariant.
__global__ __launch_bounds__(256) void agg1_kernel(const int* __restrict__ offs,
                                                   const int* __restrict__ csr,
                                                   const float* __restrict__ als,
                                                   const float* __restrict__ ald,
                                                   const unsigned short* __restrict__ h1b,
                                                   const float* __restrict__ b,
                                                   const float* __restrict__ cs2,
                                                   const float* __restrict__ cd2,
                                                   unsigned short* __restrict__ heluB,
                                                   float* __restrict__ als2,
                                                   float* __restrict__ ald2) {
    __shared__ float wsh[4][2 * MAXD];          // 4 KiB
    __shared__ int   ssh[4][MAXD];              // 2 KiB
    int lane = threadIdx.x & 63;
    int nw = threadIdx.x >> 6;
    int node = blockIdx.x * 4 + nw;
    int start = offs[node], end = offs[node + 1];
    const float2* alsv = (const float2*)als;
    float2 adv = ((const float2*)ald)[node];
    float* wn = wsh[nw];
    int* sn = ssh[nw];

    // Pass AB: weights + denom; stash (w, src) in LDS
    float s0 = 0.f, s1 = 0.f;
    for (int j = start + lane; j < end; j += 64) {
        int idx = j - start;
        int s = csr[j];
        float2 a = alsv[s];
        float e0 = a.x + adv.x; e0 = e0 > 0.f ? e0 : NEG * e0;
        float e1 = a.y + adv.y; e1 = e1 > 0.f ? e1 : NEG * e1;
        float w0 = expf(e0), w1 = expf(e1);
        s0 += w0; s1 += w1;
        if (idx < MAXD) { wn[idx * 2] = w0; wn[idx * 2 + 1] = w1; sn[idx] = s; }
    }
    for (int mm = 32; mm; mm >>= 1) { s0 += __shfl_xor(s0, mm); s1 += __shfl_xor(s1, mm); }
    float inv0 = 1.f / (s0 + 1e-16f), inv1 = 1.f / (s1 + 1e-16f);

    // Pass C: gather. half-wave = one edge; 4x unroll = 8 edges/iter.
    int half = lane >> 5, l5 = lane & 31, hh = l5 >> 4;
    const ushort4* h14 = (const ushort4*)h1b;
    float4 acc = make_float4(0.f, 0.f, 0.f, 0.f);
    int j2 = start;
#define AGG1_FETCH(jv_, sv_, wv_) { \
        int idx_ = (jv_) - start; \
        if (idx_ < MAXD) { sv_ = sn[idx_]; wv_ = wn[idx_ * 2 + hh]; } \
        else { sv_ = csr[jv_]; float2 a_ = alsv[sv_]; \
               float e_ = (hh ? a_.y + adv.y : a_.x + adv.x); e_ = e_ > 0.f ? e_ : NEG * e_; wv_ = expf(e_); } }
    for (; j2 + 8 <= end; j2 += 8) {
        int jA = j2 + half, jB = jA + 2, jC = jA + 4, jD = jA + 6;
        int sA, sB, sC, sD; float wA, wB, wC, wD;
        AGG1_FETCH(jA, sA, wA); AGG1_FETCH(jB, sB, wB);
        AGG1_FETCH(jC, sC, wC); AGG1_FETCH(jD, sD, wD);
        float4 hA = b2f4(h14[sA * 32 + l5]);    // 4 independent 256B gathers in flight
        float4 hB = b2f4(h14[sB * 32 + l5]);
        float4 hC = b2f4(h14[sC * 32 + l5]);
        float4 hD = b2f4(h14[sD * 32 + l5]);
        FMA4(acc, wA, hA);
        FMA4(acc, wB, hB);
        FMA4(acc, wC, hC);
        FMA4(acc, wD, hD);
    }
    for (; j2 < end; j2 += 2) {
        int j = j2 + half;
        if (j < end) {
            int s; float w;
            AGG1_FETCH(j, s, w);
            float4 hv = b2f4(h14[s * 32 + l5]);
            FMA4(acc, w, hv);
        }
    }
#undef AGG1_FETCH
    acc.x += __shfl_xor(acc.x, 32); acc.y += __shfl_xor(acc.y, 32);
    acc.z += __shfl_xor(acc.z, 32); acc.w += __shfl_xor(acc.w, 32);
    if (lane < 32) {
        float inv = hh ? inv1 : inv0;
        float4 bb = ((const float4*)b)[l5];
        float4 o;
        o.x = fmaf(acc.x, inv, bb.x); o.y = fmaf(acc.y, inv, bb.y);
        o.z = fmaf(acc.z, inv, bb.z); o.w = fmaf(acc.w, inv, bb.w);
        o.x = o.x > 0.f ? o.x : expm1f(o.x); o.y = o.y > 0.f ? o.y : expm1f(o.y);
        o.z = o.z > 0.f ? o.z : expm1f(o.z); o.w = o.w > 0.f ? o.w : expm1f(o.w);
        ((ushort4*)heluB)[node * 32 + l5] = f2b4(o);

        // fused layer-2 attention scalars from fp32 o: als2 = helu . (W2 @ a_s2)
        float4 cs = ((const float4*)cs2)[l5];
        float4 cd = ((const float4*)cd2)[l5];
        float ps = o.x * cs.x + o.y * cs.y + o.z * cs.z + o.w * cs.w;
        float pd = o.x * cd.x + o.y * cd.y + o.z * cd.z + o.w * cd.w;
#pragma unroll
        for (int mm = 1; mm <= 16; mm <<= 1) { ps += __shfl_xor(ps, mm); pd += __shfl_xor(pd, mm); }
        if (l5 == 0) { als2[node] = ps; ald2[node] = pd; }
    }
}

// ---------------- Aggregation layer 2 (+bias) fused log_softmax ----------------
// Pass AB as above; pass C: 10-lane group = one edge (80B bf16 row, ushort4/lane),
// 2x unroll = 12 gathers in flight; per-wave LDS buffer for cross-group reduction.
__global__ __launch_bounds__(256) void agg2_kernel(const int* __restrict__ offs,
                                                   const int* __restrict__ csr,
                                                   const float* __restrict__ als,
                                                   const float* __restrict__ ald,
                                                   const unsigned short* __restrict__ h2b,
                                                   const float* __restrict__ b,
                                                   float* __restrict__ out) {
    __shared__ float  wsh[4][MAXD];             // 2 KiB
    __shared__ int    ssh[4][MAXD];             // 2 KiB
    __shared__ float4 red[4][6][10];            // 3.75 KiB
    int lane = threadIdx.x & 63;
    int nw = threadIdx.x >> 6;
    int node = blockIdx.x * 4 + nw;
    int start = offs[node], end = offs[node + 1];
    float ad = ald[node];
    float* wn = wsh[nw];
    int* sn = ssh[nw];

    float ssum = 0.f;
    for (int j = start + lane; j < end; j += 64) {
        int idx = j - start;
        int s = csr[j];
        float e = als[s] + ad; e = e > 0.f ? e : NEG * e;
        float w = expf(e);
        ssum += w;
        if (idx < MAXD) { wn[idx] = w; sn[idx] = s; }
    }
    for (int mm = 32; mm; mm >>= 1) ssum += __shfl_xor(ssum, mm);
    float inv = 1.f / (ssum + 1e-16f);

    int g = lane / 10, c = lane % 10;           // 6 groups of 10 lanes; 60..63 idle
    const ushort4* h24 = (const ushort4*)h2b;
#define AGG2_FETCH(jv_, sv_, wv_) { \
        int idx_ = (jv_) - start; \
        if (idx_ < MAXD) { sv_ = sn[idx_]; wv_ = wn[idx_]; } \
        else { sv_ = csr[jv_]; float e_ = als[sv_] + ad; e_ = e_ > 0.f ? e_ : NEG * e_; wv_ = expf(e_); } }
    if (g < 6) {
        float4 acc = make_float4(0.f, 0.f, 0.f, 0.f);
        int j2 = start;
        for (; j2 + 12 <= end; j2 += 12) {
            int jA = j2 + g, jB = jA + 6;
            int sA, sB; float wA, wB;
            AGG2_FETCH(jA, sA, wA); AGG2_FETCH(jB, sB, wB);
            float4 hA = b2f4(h24[sA * 10 + c]); // 2 independent 80B gathers in flight
            float4 hB = b2f4(h24[sB * 10 + c]);
            FMA4(acc, wA, hA);
            FMA4(acc, wB, hB);
        }
        for (; j2 < end; j2 += 6) {
            int j = j2 + g;
            if (j < end) {
                int s; float w;
                AGG2_FETCH(j, s, w);
                float4 hv = b2f4(h24[s * 10 + c]);
                FMA4(acc, w, hv);
            }
        }
        red[nw][g][c] = acc;                    // same-wave DS ordering; no barrier needed
    }
#undef AGG2_FETCH

    if (lane < 16) {
        bool act = lane < 10;
        float4 o = make_float4(-1e30f, -1e30f, -1e30f, -1e30f);
        if (act) {
            float4 tot = make_float4(0.f, 0.f, 0.f, 0.f);
#pragma unroll
            for (int k = 0; k < 6; ++k) {
                float4 r = red[nw][k][lane];
                tot.x += r.x; tot.y += r.y; tot.z += r.z; tot.w += r.w;
            }
            float4 bb = ((const float4*)b)[lane];
            o.x = fmaf(tot.x, inv, bb.x); o.y = fmaf(tot.y, inv, bb.y);
            o.z = fmaf(tot.z, inv, bb.z); o.w = fmaf(tot.w, inv, bb.w);
        }
        // log_softmax over 40 classes within lanes 0..15 (10 active, 6 neutral)
        float mx = fmaxf(fmaxf(o.x, o.y), fmaxf(o.z, o.w));
#pragma unroll
        for (int mm = 1; mm <= 8; mm <<= 1) mx = fmaxf(mx, __shfl_xor(mx, mm));
        float es = (expf(o.x - mx) + expf(o.y - mx)) + (expf(o.z - mx) + expf(o.w - mx));
#pragma unroll
        for (int mm = 1; mm <= 8; mm <<= 1) es += __shfl_xor(es, mm);
        float lse = mx + logf(es);
        if (act) {
            float4 r;
            r.x = o.x - lse; r.y = o.y - lse; r.z = o.z - lse; r.w = o.w - lse;
            ((float4*)out)[node * 10 + lane] = r;
        }
    }
}

// ---------------- launch ----------------
extern "C" void kernel_launch(void* const* d_in, const int* in_sizes, int n_in,
                              void* d_out, int out_size, void* d_ws, size_t ws_size,
                              hipStream_t stream) {
    const float* x   = (const float*)d_in[0];
    const int*   ei  = (const int*)  d_in[1];
    const float* W1  = (const float*)d_in[2];
    const float* as1 = (const float*)d_in[3];
    const float* ad1 = (const float*)d_in[4];
    const float* b1  = (const float*)d_in[5];
    const float* W2  = (const float*)d_in[6];
    const float* as2 = (const float*)d_in[7];
    const float* ad2 = (const float*)d_in[8];
    const float* b2  = (const float*)d_in[9];
    float* out = (float*)d_out;

    // workspace carve-up
    char* p = (char*)d_ws;
    auto alloc = [&](size_t bytes) { void* r = (void*)p; p += (bytes + 255) & ~size_t(255); return r; };
    unsigned short* h1b   = (unsigned short*)alloc(sizeof(unsigned short) * NN * 128);
    unsigned short* heluB = (unsigned short*)alloc(sizeof(unsigned short) * NN * 128);
    unsigned short* h2b   = (unsigned short*)alloc(sizeof(unsigned short) * NN * 40);
    float* als1 = (float*)alloc(sizeof(float) * NN * 2);
    float* ald1 = (float*)alloc(sizeof(float) * NN * 2);
    float* als2 = (float*)alloc(sizeof(float) * NN);
    float* ald2 = (float*)alloc(sizeof(float) * NN);
    float* cs2  = (float*)alloc(sizeof(float) * 128);
    float* cd2  = (float*)alloc(sizeof(float) * 128);
    int*   deg  = (int*)  alloc(sizeof(int) * NN);
    int*   cur  = (int*)  alloc(sizeof(int) * NN);
    int*   offs = (int*)  alloc(sizeof(int) * (NN + 1));
    int*   bsum = (int*)  alloc(sizeof(int) * 128);
    int*   csr  = (int*)  alloc(sizeof(int) * E2);

    // tiny precompute (independent)
    cvec_kernel<<<1, 128, 0, stream>>>(W2, as2, ad2, cs2, cd2);

    // CSR build (dst-sorted adjacency)
    hipMemsetAsync(deg, 0, sizeof(int) * NN, stream);
    count_kernel<<<(E2 / 4 + 255) / 256, 256, 0, stream>>>(ei, deg);
    scan1_kernel<<<98, 256, 0, stream>>>(deg, offs, bsum);
    scan2_kernel<<<1, 128, 0, stream>>>(bsum, offs);
    scan3_kernel<<<(NN + 255) / 256, 256, 0, stream>>>(offs, bsum);
    hipMemcpyAsync(cur, offs, sizeof(int) * NN, hipMemcpyDeviceToDevice, stream);
    place_kernel<<<(E2 / 4 + 255) / 256, 256, 0, stream>>>(ei, cur, csr);

    // Layer 1
    gemm1_kernel<<<3125, 256, 0, stream>>>(x, W1, as1, ad1, h1b, als1, ald1);
    agg1_kernel<<<25000, 256, 0, stream>>>(offs, csr, als1, ald1, h1b, b1, cs2, cd2,
                                           heluB, als2, ald2);

    // Layer 2
    gemm2_kernel<<<1000, 256, 0, stream>>>(heluB, W2, h2b);
    agg2_kernel<<<25000, 256, 0, stream>>>(offs, csr, als2, ald2, h2b, b2, out);
}

// Round 7
// 435.448 us; speedup vs baseline: 1.9231x; 1.2239x over previous
//
#include <hip/hip_runtime.h>
#include <math.h>

// Problem constants (fixed by the reference)
#define NN   100000           // nodes
#define NE   1600000          // edges (before self-loops)
#define E2   (NE + NN)        // edges incl. self-loops = 1,700,000
#define NC   40
#define NEG  0.2f
#define MAXD 128              // per-node LDS edge buffer (deg ~ Poisson(16)+1; P(>128) ~ 1e-60)

// NOTE: macro parameter names must not collide with .x/.y/.z/.w member tokens.
#define FMA4(acc_, s_, w_) { (acc_).x = fmaf((s_),(w_).x,(acc_).x); (acc_).y = fmaf((s_),(w_).y,(acc_).y); \
                             (acc_).z = fmaf((s_),(w_).z,(acc_).z); (acc_).w = fmaf((s_),(w_).w,(acc_).w); }

// bf16 <-> f32 helpers (RNE pack; plain shift unpack)
__device__ inline float b2f(unsigned short u) {
    union { unsigned int i; float f; } v; v.i = (unsigned int)u << 16; return v.f;
}
__device__ inline float4 b2f4(ushort4 u) {
    return make_float4(b2f(u.x), b2f(u.y), b2f(u.z), b2f(u.w));
}
__device__ inline unsigned short f2b(float f) {
    union { float f; unsigned int i; } v; v.f = f;
    unsigned int r = (v.i + 0x7FFFu + ((v.i >> 16) & 1u)) >> 16;
    return (unsigned short)r;
}
__device__ inline ushort4 f2b4(float4 f) {
    return make_ushort4(f2b(f.x), f2b(f.y), f2b(f.z), f2b(f.w));
}

// ---------------- GEMM1: h1b = bf16(x @ W1)  [NN,128]x[128,128], fused al1 epilogue --------
// W1 staged in TWO 32 KiB halves (K-split) -> LDS 32 KiB. als/ald from fp32 accumulators.
__global__ __launch_bounds__(256) void gemm1_kernel(const float* __restrict__ x,
                                                    const float* __restrict__ W,
                                                    const float* __restrict__ a_s,
                                                    const float* __restrict__ a_d,
                                                    unsigned short* __restrict__ h1b,
                                                    float* __restrict__ als,
                                                    float* __restrict__ ald) {
    __shared__ float Ws[64 * 128];             // 32 KiB (one K-half of W1)
    const float4* W4 = (const float4*)W;
    float4* Ws4 = (float4*)Ws;

    int cg = threadIdx.x & 31;                 // cols 4cg..4cg+3
    int rg = threadIdx.x >> 5;                 // 8 row groups x 4 rows
    int lane = threadIdx.x & 63;
    int row0 = blockIdx.x * 32 + rg * 4;       // 3125 blocks
    const float4* x4 = (const float4*)x;

    float4 acc[4];
    acc[0] = acc[1] = acc[2] = acc[3] = make_float4(0.f, 0.f, 0.f, 0.f);

    for (int ph = 0; ph < 2; ++ph) {
        if (ph) __syncthreads();               // previous half fully consumed
        for (int i = threadIdx.x; i < 2048; i += 256) Ws4[i] = W4[ph * 2048 + i];
        __syncthreads();
        for (int k4 = 0; k4 < 16; ++k4) {
            float4 wv0 = Ws4[(k4 * 4 + 0) * 32 + cg];
            float4 wv1 = Ws4[(k4 * 4 + 1) * 32 + cg];
            float4 wv2 = Ws4[(k4 * 4 + 2) * 32 + cg];
            float4 wv3 = Ws4[(k4 * 4 + 3) * 32 + cg];
#pragma unroll
            for (int r = 0; r < 4; ++r) {
                float4 xv = x4[(row0 + r) * 32 + ph * 16 + k4];  // broadcast within row group
                FMA4(acc[r], xv.x, wv0);
                FMA4(acc[r], xv.y, wv1);
                FMA4(acc[r], xv.z, wv2);
                FMA4(acc[r], xv.w, wv3);
            }
        }
    }
    ushort4* o4 = (ushort4*)h1b;
#pragma unroll
    for (int r = 0; r < 4; ++r) o4[(row0 + r) * 32 + cg] = f2b4(acc[r]);

    // al epilogue: als/ald per row per head; 16-lane group reduce (head = cg>>4)
    float4 asv = ((const float4*)a_s)[cg];
    float4 adv = ((const float4*)a_d)[cg];
#pragma unroll
    for (int r = 0; r < 4; ++r) {
        float ps = acc[r].x * asv.x + acc[r].y * asv.y + acc[r].z * asv.z + acc[r].w * asv.w;
        float pd = acc[r].x * adv.x + acc[r].y * adv.y + acc[r].z * adv.z + acc[r].w * adv.w;
#pragma unroll
        for (int mm = 1; mm <= 8; mm <<= 1) { ps += __shfl_xor(ps, mm); pd += __shfl_xor(pd, mm); }
        if ((lane & 15) == 0) {
            int h = cg >> 4;
            als[(row0 + r) * 2 + h] = ps;
            ald[(row0 + r) * 2 + h] = pd;
        }
    }
}

// ---------------- GEMM2: h2b = bf16(heluB @ W2)   [NN,128] x [128,40] ----------------
__global__ __launch_bounds__(256) void gemm2_kernel(const unsigned short* __restrict__ heluB,
                                                    const float* __restrict__ W,
                                                    unsigned short* __restrict__ h2b) {
    __shared__ float Ws[128 * 40];             // 20 KiB
    const float4* W4 = (const float4*)W;
    float4* Ws4 = (float4*)Ws;
    for (int i = threadIdx.x; i < 128 * 40 / 4; i += 256) Ws4[i] = W4[i];
    __syncthreads();

    int t = threadIdx.x;
    if (t >= 250) return;                       // 10 col groups x 25 row groups
    int cg = t % 10;
    int rg = t / 10;
    int row0 = blockIdx.x * 100 + rg * 4;       // 1000 blocks
    const ushort4* x4 = (const ushort4*)heluB;

    float4 acc[4];
    acc[0] = acc[1] = acc[2] = acc[3] = make_float4(0.f, 0.f, 0.f, 0.f);

    for (int k4 = 0; k4 < 32; ++k4) {
        float4 wv0 = Ws4[(k4 * 4 + 0) * 10 + cg];
        float4 wv1 = Ws4[(k4 * 4 + 1) * 10 + cg];
        float4 wv2 = Ws4[(k4 * 4 + 2) * 10 + cg];
        float4 wv3 = Ws4[(k4 * 4 + 3) * 10 + cg];
#pragma unroll
        for (int r = 0; r < 4; ++r) {
            float4 xv = b2f4(x4[(row0 + r) * 32 + k4]);
            FMA4(acc[r], xv.x, wv0);
            FMA4(acc[r], xv.y, wv1);
            FMA4(acc[r], xv.z, wv2);
            FMA4(acc[r], xv.w, wv3);
        }
    }
    ushort4* o4 = (ushort4*)h2b;                // 40 bf16/row = 10 ushort4
#pragma unroll
    for (int r = 0; r < 4; ++r) o4[(row0 + r) * 10 + cg] = f2b4(acc[r]);
}

// ---------------- cvec: c_s2 = W2 @ a_s2, c_d2 = W2 @ a_d2  (128 threads) ----------------
__global__ void cvec_kernel(const float* __restrict__ W2,
                            const float* __restrict__ a_s2,
                            const float* __restrict__ a_d2,
                            float* __restrict__ cs2,
                            float* __restrict__ cd2) {
    int k = threadIdx.x;                        // 0..127
    float ss = 0.f, dd = 0.f;
    for (int c = 0; c < NC; ++c) {
        float wv = W2[k * NC + c];
        ss = fmaf(wv, a_s2[c], ss);
        dd = fmaf(wv, a_d2[c], dd);
    }
    cs2[k] = ss;
    cd2[k] = dd;
}

// ---------------- CSR build (by dst): ONE atomic pass ----------------
// rank_kernel: histogram + per-edge rank capture; rank stored COALESCED (int4),
// so the atomic's dependent store causes no scattered line churn.
__global__ __launch_bounds__(256) void rank_kernel(const int* __restrict__ ei,
                                                   int* __restrict__ deg,
                                                   int* __restrict__ rank) {
    int j0 = (blockIdx.x * 256 + threadIdx.x) * 4;
    if (j0 >= E2) return;
    int4 r4;
    if (j0 < NE) {                              // NE%4==0 -> branch uniform per thread
        int4 d4 = *(const int4*)&ei[NE + j0];
        r4.x = atomicAdd(&deg[d4.x], 1);
        r4.y = atomicAdd(&deg[d4.y], 1);
        r4.z = atomicAdd(&deg[d4.z], 1);
        r4.w = atomicAdd(&deg[d4.w], 1);
    } else {
        int bse = j0 - NE;
        r4.x = atomicAdd(&deg[bse], 1);
        r4.y = atomicAdd(&deg[bse + 1], 1);
        r4.z = atomicAdd(&deg[bse + 2], 1);
        r4.w = atomicAdd(&deg[bse + 3], 1);
    }
    *(int4*)&rank[j0] = r4;
}

__global__ __launch_bounds__(256) void scan1_kernel(const int* __restrict__ deg,
                                                    int* __restrict__ offs,
                                                    int* __restrict__ bsum) {
    __shared__ int sh[256];
    int base = blockIdx.x * 1024 + threadIdx.x * 4;
    int v[4];
#pragma unroll
    for (int u = 0; u < 4; ++u) { int idx = base + u; v[u] = (idx < NN) ? deg[idx] : 0; }
    int t0 = v[0] + v[1] + v[2] + v[3];
    sh[threadIdx.x] = t0;
    __syncthreads();
    for (int off = 1; off < 256; off <<= 1) {
        int a = sh[threadIdx.x];
        int b = (threadIdx.x >= off) ? sh[threadIdx.x - off] : 0;
        __syncthreads();
        sh[threadIdx.x] = a + b;
        __syncthreads();
    }
    int excl = sh[threadIdx.x] - t0;
    if (threadIdx.x == 255) bsum[blockIdx.x] = sh[255];
    int run = excl;
#pragma unroll
    for (int u = 0; u < 4; ++u) { int idx = base + u; if (idx < NN) offs[idx] = run; run += v[u]; }
}

__global__ void scan2_kernel(int* __restrict__ bsum, int* __restrict__ offs) {
    __shared__ int sh[128];
    int i = threadIdx.x;
    int v = (i < 98) ? bsum[i] : 0;
    sh[i] = v;
    __syncthreads();
    for (int off = 1; off < 128; off <<= 1) {
        int a = sh[i];
        int b = (i >= off) ? sh[i - off] : 0;
        __syncthreads();
        sh[i] = a + b;
        __syncthreads();
    }
    if (i < 98) bsum[i] = sh[i] - v;            // exclusive
    if (i == 127) offs[NN] = sh[127];           // total = E2
}

__global__ __launch_bounds__(256) void scan3_kernel(int* __restrict__ offs,
                                                    const int* __restrict__ bsum) {
    int i = blockIdx.x * 256 + threadIdx.x;
    if (i < NN) offs[i] += bsum[i >> 10];
}

// scatter_kernel: NO atomics — all loads coalesced (ei, rank) or L2-resident (offs);
// csr scatter store is fire-and-forget.
__global__ __launch_bounds__(256) void scatter_kernel(const int* __restrict__ ei,
                                                      const int* __restrict__ rank,
                                                      const int* __restrict__ offs,
                                                      int* __restrict__ csr) {
    int j0 = (blockIdx.x * 256 + threadIdx.x) * 4;
    if (j0 >= E2) return;
    int4 r4 = *(const int4*)&rank[j0];
    if (j0 < NE) {
        int4 s4 = *(const int4*)&ei[j0];
        int4 d4 = *(const int4*)&ei[NE + j0];
        csr[offs[d4.x] + r4.x] = s4.x;
        csr[offs[d4.y] + r4.y] = s4.y;
        csr[offs[d4.z] + r4.z] = s4.z;
        csr[offs[d4.w] + r4.w] = s4.w;
    } else {
        int bse = j0 - NE;
        csr[offs[bse] + r4.x]     = bse;
        csr[offs[bse + 1] + r4.y] = bse + 1;
        csr[offs[bse + 2] + r4.z] = bse + 2;
        csr[offs[bse + 3] + r4.w] = bse + 3;
    }
}

// ---------------- Aggregation layer 1 (+bias +ELU, fused als2/ald2) ----------------
// One wave per dst node. Pass AB (lane-parallel): w=exp(leaky(e)) -> LDS (w,src), sum.
// Pass C: half-wave = one edge (256B bf16 row), 4x unrolled (8 edges/iter).
// No max-subtraction: e is bounded, softmax is shift-invariant.
__global__ __launch_bounds__(256) void agg1_kernel(const int* __restrict__ offs,
                                                   const int* __restrict__ csr,
                                                   const float* __restrict__ als,
                                                   const float* __restrict__ ald,
                                                   const unsigned short* __restrict__ h1b,
                                                   const float* __restrict__ b,
                                                   const float* __restrict__ cs2,
                                                   const float* __restrict__ cd2,
                                                   unsigned short* __restrict__ heluB,
                                                   float* __restrict__ als2,
                                                   float* __restrict__ ald2) {
    __shared__ float wsh[4][2 * MAXD];          // 4 KiB
    __shared__ int   ssh[4][MAXD];              // 2 KiB
    int lane = threadIdx.x & 63;
    int nw = threadIdx.x >> 6;
    int node = blockIdx.x * 4 + nw;
    int start = offs[node], end = offs[node + 1];
    const float2* alsv = (const float2*)als;
    float2 adv = ((const float2*)ald)[node];
    float* wn = wsh[nw];
    int* sn = ssh[nw];

    // Pass AB: weights + denom; stash (w, src) in LDS
    float s0 = 0.f, s1 = 0.f;
    for (int j = start + lane; j < end; j += 64) {
        int idx = j - start;
        int s = csr[j];
        float2 a = alsv[s];
        float e0 = a.x + adv.x; e0 = e0 > 0.f ? e0 : NEG * e0;
        float e1 = a.y + adv.y; e1 = e1 > 0.f ? e1 : NEG * e1;
        float w0 = expf(e0), w1 = expf(e1);
        s0 += w0; s1 += w1;
        if (idx < MAXD) { wn[idx * 2] = w0; wn[idx * 2 + 1] = w1; sn[idx] = s; }
    }
    for (int mm = 32; mm; mm >>= 1) { s0 += __shfl_xor(s0, mm); s1 += __shfl_xor(s1, mm); }
    float inv0 = 1.f / (s0 + 1e-16f), inv1 = 1.f / (s1 + 1e-16f);

    // Pass C: gather. half-wave = one edge; 4x unroll = 8 edges/iter.
    int half = lane >> 5, l5 = lane & 31, hh = l5 >> 4;
    const ushort4* h14 = (const ushort4*)h1b;
    float4 acc = make_float4(0.f, 0.f, 0.f, 0.f);
    int j2 = start;
#define AGG1_FETCH(jv_, sv_, wv_) { \
        int idx_ = (jv_) - start; \
        if (idx_ < MAXD) { sv_ = sn[idx_]; wv_ = wn[idx_ * 2 + hh]; } \
        else { sv_ = csr[jv_]; float2 a_ = alsv[sv_]; \
               float e_ = (hh ? a_.y + adv.y : a_.x + adv.x); e_ = e_ > 0.f ? e_ : NEG * e_; wv_ = expf(e_); } }
    for (; j2 + 8 <= end; j2 += 8) {
        int jA = j2 + half, jB = jA + 2, jC = jA + 4, jD = jA + 6;
        int sA, sB, sC, sD; float wA, wB, wC, wD;
        AGG1_FETCH(jA, sA, wA); AGG1_FETCH(jB, sB, wB);
        AGG1_FETCH(jC, sC, wC); AGG1_FETCH(jD, sD, wD);
        float4 hA = b2f4(h14[sA * 32 + l5]);    // 4 independent 256B gathers in flight
        float4 hB = b2f4(h14[sB * 32 + l5]);
        float4 hC = b2f4(h14[sC * 32 + l5]);
        float4 hD = b2f4(h14[sD * 32 + l5]);
        FMA4(acc, wA, hA);
        FMA4(acc, wB, hB);
        FMA4(acc, wC, hC);
        FMA4(acc, wD, hD);
    }
    for (; j2 < end; j2 += 2) {
        int j = j2 + half;
        if (j < end) {
            int s; float w;
            AGG1_FETCH(j, s, w);
            float4 hv = b2f4(h14[s * 32 + l5]);
            FMA4(acc, w, hv);
        }
    }
#undef AGG1_FETCH
    acc.x += __shfl_xor(acc.x, 32); acc.y += __shfl_xor(acc.y, 32);
    acc.z += __shfl_xor(acc.z, 32); acc.w += __shfl_xor(acc.w, 32);
    if (lane < 32) {
        float inv = hh ? inv1 : inv0;
        float4 bb = ((const float4*)b)[l5];
        float4 o;
        o.x = fmaf(acc.x, inv, bb.x); o.y = fmaf(acc.y, inv, bb.y);
        o.z = fmaf(acc.z, inv, bb.z); o.w = fmaf(acc.w, inv, bb.w);
        o.x = o.x > 0.f ? o.x : expm1f(o.x); o.y = o.y > 0.f ? o.y : expm1f(o.y);
        o.z = o.z > 0.f ? o.z : expm1f(o.z); o.w = o.w > 0.f ? o.w : expm1f(o.w);
        ((ushort4*)heluB)[node * 32 + l5] = f2b4(o);

        // fused layer-2 attention scalars from fp32 o: als2 = helu . (W2 @ a_s2)
        float4 cs = ((const float4*)cs2)[l5];
        float4 cd = ((const float4*)cd2)[l5];
        float ps = o.x * cs.x + o.y * cs.y + o.z * cs.z + o.w * cs.w;
        float pd = o.x * cd.x + o.y * cd.y + o.z * cd.z + o.w * cd.w;
#pragma unroll
        for (int mm = 1; mm <= 16; mm <<= 1) { ps += __shfl_xor(ps, mm); pd += __shfl_xor(pd, mm); }
        if (l5 == 0) { als2[node] = ps; ald2[node] = pd; }
    }
}

// ---------------- Aggregation layer 2 (+bias) fused log_softmax ----------------
// Pass AB as above; pass C: 10-lane group = one edge (80B bf16 row, ushort4/lane),
// 2x unroll = 12 gathers in flight; per-wave LDS buffer for cross-group reduction.
__global__ __launch_bounds__(256) void agg2_kernel(const int* __restrict__ offs,
                                                   const int* __restrict__ csr,
                                                   const float* __restrict__ als,
                                                   const float* __restrict__ ald,
                                                   const unsigned short* __restrict__ h2b,
                                                   const float* __restrict__ b,
                                                   float* __restrict__ out) {
    __shared__ float  wsh[4][MAXD];             // 2 KiB
    __shared__ int    ssh[4][MAXD];             // 2 KiB
    __shared__ float4 red[4][6][10];            // 3.75 KiB
    int lane = threadIdx.x & 63;
    int nw = threadIdx.x >> 6;
    int node = blockIdx.x * 4 + nw;
    int start = offs[node], end = offs[node + 1];
    float ad = ald[node];
    float* wn = wsh[nw];
    int* sn = ssh[nw];

    float ssum = 0.f;
    for (int j = start + lane; j < end; j += 64) {
        int idx = j - start;
        int s = csr[j];
        float e = als[s] + ad; e = e > 0.f ? e : NEG * e;
        float w = expf(e);
        ssum += w;
        if (idx < MAXD) { wn[idx] = w; sn[idx] = s; }
    }
    for (int mm = 32; mm; mm >>= 1) ssum += __shfl_xor(ssum, mm);
    float inv = 1.f / (ssum + 1e-16f);

    int g = lane / 10, c = lane % 10;           // 6 groups of 10 lanes; 60..63 idle
    const ushort4* h24 = (const ushort4*)h2b;
#define AGG2_FETCH(jv_, sv_, wv_) { \
        int idx_ = (jv_) - start; \
        if (idx_ < MAXD) { sv_ = sn[idx_]; wv_ = wn[idx_]; } \
        else { sv_ = csr[jv_]; float e_ = als[sv_] + ad; e_ = e_ > 0.f ? e_ : NEG * e_; wv_ = expf(e_); } }
    if (g < 6) {
        float4 acc = make_float4(0.f, 0.f, 0.f, 0.f);
        int j2 = start;
        for (; j2 + 12 <= end; j2 += 12) {
            int jA = j2 + g, jB = jA + 6;
            int sA, sB; float wA, wB;
            AGG2_FETCH(jA, sA, wA); AGG2_FETCH(jB, sB, wB);
            float4 hA = b2f4(h24[sA * 10 + c]); // 2 independent 80B gathers in flight
            float4 hB = b2f4(h24[sB * 10 + c]);
            FMA4(acc, wA, hA);
            FMA4(acc, wB, hB);
        }
        for (; j2 < end; j2 += 6) {
            int j = j2 + g;
            if (j < end) {
                int s; float w;
                AGG2_FETCH(j, s, w);
                float4 hv = b2f4(h24[s * 10 + c]);
                FMA4(acc, w, hv);
            }
        }
        red[nw][g][c] = acc;                    // same-wave DS ordering; no barrier needed
    }
#undef AGG2_FETCH

    if (lane < 16) {
        bool act = lane < 10;
        float4 o = make_float4(-1e30f, -1e30f, -1e30f, -1e30f);
        if (act) {
            float4 tot = make_float4(0.f, 0.f, 0.f, 0.f);
#pragma unroll
            for (int k = 0; k < 6; ++k) {
                float4 r = red[nw][k][lane];
                tot.x += r.x; tot.y += r.y; tot.z += r.z; tot.w += r.w;
            }
            float4 bb = ((const float4*)b)[lane];
            o.x = fmaf(tot.x, inv, bb.x); o.y = fmaf(tot.y, inv, bb.y);
            o.z = fmaf(tot.z, inv, bb.z); o.w = fmaf(tot.w, inv, bb.w);
        }
        // log_softmax over 40 classes within lanes 0..15 (10 active, 6 neutral)
        float mx = fmaxf(fmaxf(o.x, o.y), fmaxf(o.z, o.w));
#pragma unroll
        for (int mm = 1; mm <= 8; mm <<= 1) mx = fmaxf(mx, __shfl_xor(mx, mm));
        float es = (expf(o.x - mx) + expf(o.y - mx)) + (expf(o.z - mx) + expf(o.w - mx));
#pragma unroll
        for (int mm = 1; mm <= 8; mm <<= 1) es += __shfl_xor(es, mm);
        float lse = mx + logf(es);
        if (act) {
            float4 r;
            r.x = o.x - lse; r.y = o.y - lse; r.z = o.z - lse; r.w = o.w - lse;
            ((float4*)out)[node * 10 + lane] = r;
        }
    }
}

// ---------------- launch ----------------
extern "C" void kernel_launch(void* const* d_in, const int* in_sizes, int n_in,
                              void* d_out, int out_size, void* d_ws, size_t ws_size,
                              hipStream_t stream) {
    const float* x   = (const float*)d_in[0];
    const int*   ei  = (const int*)  d_in[1];
    const float* W1  = (const float*)d_in[2];
    const float* as1 = (const float*)d_in[3];
    const float* ad1 = (const float*)d_in[4];
    const float* b1  = (const float*)d_in[5];
    const float* W2  = (const float*)d_in[6];
    const float* as2 = (const float*)d_in[7];
    const float* ad2 = (const float*)d_in[8];
    const float* b2  = (const float*)d_in[9];
    float* out = (float*)d_out;

    // workspace carve-up
    char* p = (char*)d_ws;
    auto alloc = [&](size_t bytes) { void* r = (void*)p; p += (bytes + 255) & ~size_t(255); return r; };
    unsigned short* h1b   = (unsigned short*)alloc(sizeof(unsigned short) * NN * 128);
    unsigned short* heluB = (unsigned short*)alloc(sizeof(unsigned short) * NN * 128);
    unsigned short* h2b   = (unsigned short*)alloc(sizeof(unsigned short) * NN * 40);
    float* als1 = (float*)alloc(sizeof(float) * NN * 2);
    float* ald1 = (float*)alloc(sizeof(float) * NN * 2);
    float* als2 = (float*)alloc(sizeof(float) * NN);
    float* ald2 = (float*)alloc(sizeof(float) * NN);
    float* cs2  = (float*)alloc(sizeof(float) * 128);
    float* cd2  = (float*)alloc(sizeof(float) * 128);
    int*   deg  = (int*)  alloc(sizeof(int) * NN);
    int*   offs = (int*)  alloc(sizeof(int) * (NN + 1));
    int*   bsum = (int*)  alloc(sizeof(int) * 128);
    int*   rank = (int*)  alloc(sizeof(int) * E2);
    int*   csr  = (int*)  alloc(sizeof(int) * E2);

    // tiny precompute (independent)
    cvec_kernel<<<1, 128, 0, stream>>>(W2, as2, ad2, cs2, cd2);

    // CSR build (dst-sorted adjacency) — single atomic pass
    hipMemsetAsync(deg, 0, sizeof(int) * NN, stream);
    rank_kernel<<<(E2 / 4 + 255) / 256, 256, 0, stream>>>(ei, deg, rank);
    scan1_kernel<<<98, 256, 0, stream>>>(deg, offs, bsum);
    scan2_kernel<<<1, 128, 0, stream>>>(bsum, offs);
    scan3_kernel<<<(NN + 255) / 256, 256, 0, stream>>>(offs, bsum);
    scatter_kernel<<<(E2 / 4 + 255) / 256, 256, 0, stream>>>(ei, rank, offs, csr);

    // Layer 1
    gemm1_kernel<<<3125, 256, 0, stream>>>(x, W1, as1, ad1, h1b, als1, ald1);
    agg1_kernel<<<25000, 256, 0, stream>>>(offs, csr, als1, ald1, h1b, b1, cs2, cd2,
                                           heluB, als2, ald2);

    // Layer 2
    gemm2_kernel<<<1000, 256, 0, stream>>>(heluB, W2, h2b);
    agg2_kernel<<<25000, 256, 0, stream>>>(offs, csr, als2, ald2, h2b, b2, out);
}

// Round 9
// 383.696 us; speedup vs baseline: 2.1824x; 1.1349x over previous
//
#include <hip/hip_runtime.h>
#include <math.h>

// Problem constants (fixed by the reference)
#define NN   100000           // nodes
#define NE   1600000          // edges (before self-loops)
#define E2   (NE + NN)        // edges incl. self-loops = 1,700,000
#define NC   40
#define NEG  0.2f
#define MAXD 128              // per-node LDS edge buffer (deg ~ Poisson(16)+1; P(>128) ~ 1e-60)

// NOTE: macro parameter names must not collide with .x/.y/.z/.w member tokens.
#define FMA4(acc_, s_, w_) { (acc_).x = fmaf((s_),(w_).x,(acc_).x); (acc_).y = fmaf((s_),(w_).y,(acc_).y); \
                             (acc_).z = fmaf((s_),(w_).z,(acc_).z); (acc_).w = fmaf((s_),(w_).w,(acc_).w); }

typedef __attribute__((ext_vector_type(8))) short short8;   // 8 bf16 in 4 VGPRs (MFMA A/B frag)
typedef __attribute__((ext_vector_type(4))) float f32x4;    // MFMA C/D frag

// bf16 <-> f32 helpers (RNE pack; plain shift unpack)
__device__ inline float b2f(unsigned short u) {
    union { unsigned int i; float f; } v; v.i = (unsigned int)u << 16; return v.f;
}
__device__ inline float4 b2f4(ushort4 u) {
    return make_float4(b2f(u.x), b2f(u.y), b2f(u.z), b2f(u.w));
}
__device__ inline unsigned short f2b(float f) {
    union { float f; unsigned int i; } v; v.f = f;
    unsigned int r = (v.i + 0x7FFFu + ((v.i >> 16) & 1u)) >> 16;
    return (unsigned short)r;
}
__device__ inline ushort4 f2b4(float4 f) {
    return make_ushort4(f2b(f.x), f2b(f.y), f2b(f.z), f2b(f.w));
}

// ---------------- W prep: pack hi/lo bf16 fragments in MFMA order ----------------
// frag flat index t = ((nt*4+ks)*64 + lane)*8 + j ; element W[k][col],
// k = ks*32 + (lane>>4)*8 + j, col = nt*16 + (lane&15).
__global__ void prep1_kernel(const float* __restrict__ W,
                             unsigned short* __restrict__ wh,
                             unsigned short* __restrict__ wl) {
    int t = blockIdx.x * 256 + threadIdx.x;     // 0..16383 (8 nt x 4 ks)
    int j = t & 7, lane = (t >> 3) & 63, ksnt = t >> 9;
    int ks = ksnt & 3, nt = ksnt >> 2;
    int k = ks * 32 + (lane >> 4) * 8 + j, col = nt * 16 + (lane & 15);
    float w = W[k * 128 + col];
    unsigned short h = f2b(w);
    wh[t] = h; wl[t] = f2b(w - b2f(h));
}

__global__ void prep2_kernel(const float* __restrict__ W,
                             unsigned short* __restrict__ wh,
                             unsigned short* __restrict__ wl) {
    int t = blockIdx.x * 256 + threadIdx.x;     // 0..6143 (3 nt x 4 ks), N padded 40->48
    int j = t & 7, lane = (t >> 3) & 63, ksnt = t >> 9;
    int ks = ksnt & 3, nt = ksnt >> 2;
    int k = ks * 32 + (lane >> 4) * 8 + j, col = nt * 16 + (lane & 15);
    float w = (col < NC) ? W[k * NC + col] : 0.f;
    unsigned short h = f2b(w);
    wh[t] = h; wl[t] = f2b(w - b2f(h));
}

// ---------------- GEMM1 (MFMA): h1b = bf16(x @ W1), fused al1 epilogue ----------------
// Split precision: x=xh+xl, W=Wh+Wl (bf16); h ~= xh*Wh + xl*Wh + xh*Wl (fp32-equiv).
// One wave = 16-row stripe x 128 cols: 8 n-tiles x 4 k-steps x 3 MFMAs = 96 MFMAs.
__global__ __launch_bounds__(256) void gemm1_mfma(const float* __restrict__ x,
                                                  const unsigned short* __restrict__ wh,
                                                  const unsigned short* __restrict__ wl,
                                                  const float* __restrict__ a_s,
                                                  const float* __restrict__ a_d,
                                                  unsigned short* __restrict__ h1b,
                                                  float* __restrict__ als,
                                                  float* __restrict__ ald) {
    __shared__ unsigned short whs[16384];       // 32 KiB
    __shared__ unsigned short wls[16384];       // 32 KiB
    {
        const uint4* g1 = (const uint4*)wh; const uint4* g2 = (const uint4*)wl;
        uint4* s1 = (uint4*)whs; uint4* s2 = (uint4*)wls;
        for (int i = threadIdx.x; i < 2048; i += 256) { s1[i] = g1[i]; s2[i] = g2[i]; }
    }
    __syncthreads();
    int wv = threadIdx.x >> 6, lane = threadIdx.x & 63;
    int stripe = blockIdx.x * 4 + wv;           // 1563 blocks; 6250 stripes of 16 rows
    if (stripe >= 6250) return;
    int row0 = stripe * 16;
    int mrow = lane & 15, kg = lane >> 4;       // A row / B-D col = lane&15; k-group = lane>>4

    f32x4 acc[8];
#pragma unroll
    for (int i = 0; i < 8; ++i) acc[i] = (f32x4){0.f, 0.f, 0.f, 0.f};

    const float* xrow = x + (size_t)(row0 + mrow) * 128;
    for (int ks = 0; ks < 4; ++ks) {
        float4 v0 = *(const float4*)(xrow + ks * 32 + kg * 8);
        float4 v1 = *(const float4*)(xrow + ks * 32 + kg * 8 + 4);
        float vv[8] = {v0.x, v0.y, v0.z, v0.w, v1.x, v1.y, v1.z, v1.w};
        short8 ah, alo;
#pragma unroll
        for (int j = 0; j < 8; ++j) {
            unsigned short h = f2b(vv[j]);
            ah[j]  = (short)h;
            alo[j] = (short)f2b(vv[j] - b2f(h));
        }
#pragma unroll
        for (int nt = 0; nt < 8; ++nt) {
            short8 bh = *(const short8*)(whs + ((nt * 4 + ks) * 64 + lane) * 8);
            short8 bl = *(const short8*)(wls + ((nt * 4 + ks) * 64 + lane) * 8);
            acc[nt] = __builtin_amdgcn_mfma_f32_16x16x32_bf16(ah,  bh, acc[nt], 0, 0, 0);
            acc[nt] = __builtin_amdgcn_mfma_f32_16x16x32_bf16(alo, bh, acc[nt], 0, 0, 0);
            acc[nt] = __builtin_amdgcn_mfma_f32_16x16x32_bf16(ah,  bl, acc[nt], 0, 0, 0);
        }
    }

    // D layout: row = row0 + kg*4 + r, col = nt*16 + mrow  [guide m89]
#pragma unroll
    for (int r = 0; r < 4; ++r) {
        int row = row0 + kg * 4 + r;
#pragma unroll
        for (int nt = 0; nt < 8; ++nt)
            h1b[(size_t)row * 128 + nt * 16 + mrow] = f2b(acc[nt][r]);
        // fused al epilogue from fp32 accumulators (head0 = cols 0..63, head1 = 64..127)
        float ps0 = 0.f, pd0 = 0.f, ps1 = 0.f, pd1 = 0.f;
#pragma unroll
        for (int nt = 0; nt < 4; ++nt) {
            float av = a_s[nt * 16 + mrow], dv = a_d[nt * 16 + mrow];
            ps0 = fmaf(acc[nt][r], av, ps0); pd0 = fmaf(acc[nt][r], dv, pd0);
        }
#pragma unroll
        for (int nt = 4; nt < 8; ++nt) {
            float av = a_s[nt * 16 + mrow], dv = a_d[nt * 16 + mrow];
            ps1 = fmaf(acc[nt][r], av, ps1); pd1 = fmaf(acc[nt][r], dv, pd1);
        }
#pragma unroll
        for (int mm = 1; mm <= 8; mm <<= 1) {
            ps0 += __shfl_xor(ps0, mm); pd0 += __shfl_xor(pd0, mm);
            ps1 += __shfl_xor(ps1, mm); pd1 += __shfl_xor(pd1, mm);
        }
        if (mrow == 0) {
            als[row * 2]     = ps0; ald[row * 2]     = pd0;
            als[row * 2 + 1] = ps1; ald[row * 2 + 1] = pd1;
        }
    }
}

// ---------------- GEMM2 (MFMA): h2b = bf16(heluB @ W2)  [NN,128]x[128,40] ----------------
// A is already bf16 (heluB) -> load fragments directly; W2 split hi/lo (2 MFMAs each).
__global__ __launch_bounds__(256) void gemm2_mfma(const unsigned short* __restrict__ heluB,
                                                  const unsigned short* __restrict__ wh,
                                                  const unsigned short* __restrict__ wl,
                                                  unsigned short* __restrict__ h2b) {
    __shared__ unsigned short whs[6144];        // 12 KiB
    __shared__ unsigned short wls[6144];        // 12 KiB
    {
        const uint4* g1 = (const uint4*)wh; const uint4* g2 = (const uint4*)wl;
        uint4* s1 = (uint4*)whs; uint4* s2 = (uint4*)wls;
        for (int i = threadIdx.x; i < 768; i += 256) { s1[i] = g1[i]; s2[i] = g2[i]; }
    }
    __syncthreads();
    int wv = threadIdx.x >> 6, lane = threadIdx.x & 63;
    int stripe = blockIdx.x * 4 + wv;
    if (stripe >= 6250) return;
    int row0 = stripe * 16;
    int mrow = lane & 15, kg = lane >> 4;

    f32x4 acc[3];
#pragma unroll
    for (int i = 0; i < 3; ++i) acc[i] = (f32x4){0.f, 0.f, 0.f, 0.f};

    const unsigned short* arow = heluB + (size_t)(row0 + mrow) * 128;
    for (int ks = 0; ks < 4; ++ks) {
        short8 a = *(const short8*)(arow + ks * 32 + kg * 8);   // 8 bf16, 16B aligned
#pragma unroll
        for (int nt = 0; nt < 3; ++nt) {
            short8 bh = *(const short8*)(whs + ((nt * 4 + ks) * 64 + lane) * 8);
            short8 bl = *(const short8*)(wls + ((nt * 4 + ks) * 64 + lane) * 8);
            acc[nt] = __builtin_amdgcn_mfma_f32_16x16x32_bf16(a, bh, acc[nt], 0, 0, 0);
            acc[nt] = __builtin_amdgcn_mfma_f32_16x16x32_bf16(a, bl, acc[nt], 0, 0, 0);
        }
    }
#pragma unroll
    for (int r = 0; r < 4; ++r) {
        int row = row0 + kg * 4 + r;
        h2b[(size_t)row * 40 + mrow]      = f2b(acc[0][r]);
        h2b[(size_t)row * 40 + 16 + mrow] = f2b(acc[1][r]);
        if (mrow < 8) h2b[(size_t)row * 40 + 32 + mrow] = f2b(acc[2][r]);
    }
}

// ---------------- cvec: c_s2 = W2 @ a_s2, c_d2 = W2 @ a_d2  (128 threads) ----------------
__global__ void cvec_kernel(const float* __restrict__ W2,
                            const float* __restrict__ a_s2,
                            const float* __restrict__ a_d2,
                            float* __restrict__ cs2,
                            float* __restrict__ cd2) {
    int k = threadIdx.x;                        // 0..127
    float ss = 0.f, dd = 0.f;
    for (int c = 0; c < NC; ++c) {
        float wv = W2[k * NC + c];
        ss = fmaf(wv, a_s2[c], ss);
        dd = fmaf(wv, a_d2[c], dd);
    }
    cs2[k] = ss;
    cd2[k] = dd;
}

// ---------------- CSR build (by dst): ONE atomic pass ----------------
__global__ __launch_bounds__(256) void rank_kernel(const int* __restrict__ ei,
                                                   int* __restrict__ deg,
                                                   int* __restrict__ rank) {
    int j0 = (blockIdx.x * 256 + threadIdx.x) * 4;
    if (j0 >= E2) return;
    int4 r4;
    if (j0 < NE) {                              // NE%4==0 -> branch uniform per thread
        int4 d4 = *(const int4*)&ei[NE + j0];
        r4.x = atomicAdd(&deg[d4.x], 1);
        r4.y = atomicAdd(&deg[d4.y], 1);
        r4.z = atomicAdd(&deg[d4.z], 1);
        r4.w = atomicAdd(&deg[d4.w], 1);
    } else {
        int bse = j0 - NE;
        r4.x = atomicAdd(&deg[bse], 1);
        r4.y = atomicAdd(&deg[bse + 1], 1);
        r4.z = atomicAdd(&deg[bse + 2], 1);
        r4.w = atomicAdd(&deg[bse + 3], 1);
    }
    *(int4*)&rank[j0] = r4;
}

__global__ __launch_bounds__(256) void scan1_kernel(const int* __restrict__ deg,
                                                    int* __restrict__ offs,
                                                    int* __restrict__ bsum) {
    __shared__ int sh[256];
    int base = blockIdx.x * 1024 + threadIdx.x * 4;
    int v[4];
#pragma unroll
    for (int u = 0; u < 4; ++u) { int idx = base + u; v[u] = (idx < NN) ? deg[idx] : 0; }
    int t0 = v[0] + v[1] + v[2] + v[3];
    sh[threadIdx.x] = t0;
    __syncthreads();
    for (int off = 1; off < 256; off <<= 1) {
        int a = sh[threadIdx.x];
        int b = (threadIdx.x >= off) ? sh[threadIdx.x - off] : 0;
        __syncthreads();
        sh[threadIdx.x] = a + b;
        __syncthreads();
    }
    int excl = sh[threadIdx.x] - t0;
    if (threadIdx.x == 255) bsum[blockIdx.x] = sh[255];
    int run = excl;
#pragma unroll
    for (int u = 0; u < 4; ++u) { int idx = base + u; if (idx < NN) offs[idx] = run; run += v[u]; }
}

__global__ void scan2_kernel(int* __restrict__ bsum, int* __restrict__ offs) {
    __shared__ int sh[128];
    int i = threadIdx.x;
    int v = (i < 98) ? bsum[i] : 0;
    sh[i] = v;
    __syncthreads();
    for (int off = 1; off < 128; off <<= 1) {
        int a = sh[i];
        int b = (i >= off) ? sh[i - off] : 0;
        __syncthreads();
        sh[i] = a + b;
        __syncthreads();
    }
    if (i < 98) bsum[i] = sh[i] - v;            // exclusive
    if (i == 127) offs[NN] = sh[127];           // total = E2
}

__global__ __launch_bounds__(256) void scan3_kernel(int* __restrict__ offs,
                                                    const int* __restrict__ bsum) {
    int i = blockIdx.x * 256 + threadIdx.x;
    if (i < NN) offs[i] += bsum[i >> 10];
}

__global__ __launch_bounds__(256) void scatter_kernel(const int* __restrict__ ei,
                                                      const int* __restrict__ rank,
                                                      const int* __restrict__ offs,
                                                      int* __restrict__ csr) {
    int j0 = (blockIdx.x * 256 + threadIdx.x) * 4;
    if (j0 >= E2) return;
    int4 r4 = *(const int4*)&rank[j0];
    if (j0 < NE) {
        int4 s4 = *(const int4*)&ei[j0];
        int4 d4 = *(const int4*)&ei[NE + j0];
        csr[offs[d4.x] + r4.x] = s4.x;
        csr[offs[d4.y] + r4.y] = s4.y;
        csr[offs[d4.z] + r4.z] = s4.z;
        csr[offs[d4.w] + r4.w] = s4.w;
    } else {
        int bse = j0 - NE;
        csr[offs[bse] + r4.x]     = bse;
        csr[offs[bse + 1] + r4.y] = bse + 1;
        csr[offs[bse + 2] + r4.z] = bse + 2;
        csr[offs[bse + 3] + r4.w] = bse + 3;
    }
}

// ---------------- Aggregation layer 1 (+bias +ELU, fused als2/ald2) ----------------
__global__ __launch_bounds__(256) void agg1_kernel(const int* __restrict__ offs,
                                                   const int* __restrict__ csr,
                                                   const float* __restrict__ als,
                                                   const float* __restrict__ ald,
                                                   const unsigned short* __restrict__ h1b,
                                                   const float* __restrict__ b,
                                                   const float* __restrict__ cs2,
                                                   const float* __restrict__ cd2,
                                                   unsigned short* __restrict__ heluB,
                                                   float* __restrict__ als2,
                                                   float* __restrict__ ald2) {
    __shared__ float wsh[4][2 * MAXD];          // 4 KiB
    __shared__ int   ssh[4][MAXD];              // 2 KiB
    int lane = threadIdx.x & 63;
    int nw = threadIdx.x >> 6;
    int node = blockIdx.x * 4 + nw;
    int start = offs[node], end = offs[node + 1];
    const float2* alsv = (const float2*)als;
    float2 adv = ((const float2*)ald)[node];
    float* wn = wsh[nw];
    int* sn = ssh[nw];

    // Pass AB: weights + denom; stash (w, src) in LDS
    float s0 = 0.f, s1 = 0.f;
    for (int j = start + lane; j < end; j += 64) {
        int idx = j - start;
        int s = csr[j];
        float2 a = alsv[s];
        float e0 = a.x + adv.x; e0 = e0 > 0.f ? e0 : NEG * e0;
        float e1 = a.y + adv.y; e1 = e1 > 0.f ? e1 : NEG * e1;
        float w0 = expf(e0), w1 = expf(e1);
        s0 += w0; s1 += w1;
        if (idx < MAXD) { wn[idx * 2] = w0; wn[idx * 2 + 1] = w1; sn[idx] = s; }
    }
    for (int mm = 32; mm; mm >>= 1) { s0 += __shfl_xor(s0, mm); s1 += __shfl_xor(s1, mm); }
    float inv0 = 1.f / (s0 + 1e-16f), inv1 = 1.f / (s1 + 1e-16f);

    // Pass C: gather. half-wave = one edge; 4x unroll = 8 edges/iter.
    int half = lane >> 5, l5 = lane & 31, hh = l5 >> 4;
    const ushort4* h14 = (const ushort4*)h1b;
    float4 acc = make_float4(0.f, 0.f, 0.f, 0.f);
    int j2 = start;
#define AGG1_FETCH(jv_, sv_, wv_) { \
        int idx_ = (jv_) - start; \
        if (idx_ < MAXD) { sv_ = sn[idx_]; wv_ = wn[idx_ * 2 + hh]; } \
        else { sv_ = csr[jv_]; float2 a_ = alsv[sv_]; \
               float e_ = (hh ? a_.y + adv.y : a_.x + adv.x); e_ = e_ > 0.f ? e_ : NEG * e_; wv_ = expf(e_); } }
    for (; j2 + 8 <= end; j2 += 8) {
        int jA = j2 + half, jB = jA + 2, jC = jA + 4, jD = jA + 6;
        int sA, sB, sC, sD; float wA, wB, wC, wD;
        AGG1_FETCH(jA, sA, wA); AGG1_FETCH(jB, sB, wB);
        AGG1_FETCH(jC, sC, wC); AGG1_FETCH(jD, sD, wD);
        float4 hA = b2f4(h14[sA * 32 + l5]);    // 4 independent 256B gathers in flight
        float4 hB = b2f4(h14[sB * 32 + l5]);
        float4 hC = b2f4(h14[sC * 32 + l5]);
        float4 hD = b2f4(h14[sD * 32 + l5]);
        FMA4(acc, wA, hA);
        FMA4(acc, wB, hB);
        FMA4(acc, wC, hC);
        FMA4(acc, wD, hD);
    }
    for (; j2 < end; j2 += 2) {
        int j = j2 + half;
        if (j < end) {
            int s; float w;
            AGG1_FETCH(j, s, w);
            float4 hv = b2f4(h14[s * 32 + l5]);
            FMA4(acc, w, hv);
        }
    }
#undef AGG1_FETCH
    acc.x += __shfl_xor(acc.x, 32); acc.y += __shfl_xor(acc.y, 32);
    acc.z += __shfl_xor(acc.z, 32); acc.w += __shfl_xor(acc.w, 32);
    if (lane < 32) {
        float inv = hh ? inv1 : inv0;
        float4 bb = ((const float4*)b)[l5];
        float4 o;
        o.x = fmaf(acc.x, inv, bb.x); o.y = fmaf(acc.y, inv, bb.y);
        o.z = fmaf(acc.z, inv, bb.z); o.w = fmaf(acc.w, inv, bb.w);
        o.x = o.x > 0.f ? o.x : expm1f(o.x); o.y = o.y > 0.f ? o.y : expm1f(o.y);
        o.z = o.z > 0.f ? o.z : expm1f(o.z); o.w = o.w > 0.f ? o.w : expm1f(o.w);
        ((ushort4*)heluB)[node * 32 + l5] = f2b4(o);

        // fused layer-2 attention scalars from fp32 o: als2 = helu . (W2 @ a_s2)
        float4 cs = ((const float4*)cs2)[l5];
        float4 cd = ((const float4*)cd2)[l5];
        float ps = o.x * cs.x + o.y * cs.y + o.z * cs.z + o.w * cs.w;
        float pd = o.x * cd.x + o.y * cd.y + o.z * cd.z + o.w * cd.w;
#pragma unroll
        for (int mm = 1; mm <= 16; mm <<= 1) { ps += __shfl_xor(ps, mm); pd += __shfl_xor(pd, mm); }
        if (l5 == 0) { als2[node] = ps; ald2[node] = pd; }
    }
}

// ---------------- Aggregation layer 2 (+bias) fused log_softmax ----------------
__global__ __launch_bounds__(256) void agg2_kernel(const int* __restrict__ offs,
                                                   const int* __restrict__ csr,
                                                   const float* __restrict__ als,
                                                   const float* __restrict__ ald,
                                                   const unsigned short* __restrict__ h2b,
                                                   const float* __restrict__ b,
                                                   float* __restrict__ out) {
    __shared__ float  wsh[4][MAXD];             // 2 KiB
    __shared__ int    ssh[4][MAXD];             // 2 KiB
    __shared__ float4 red[4][6][10];            // 3.75 KiB
    int lane = threadIdx.x & 63;
    int nw = threadIdx.x >> 6;
    int node = blockIdx.x * 4 + nw;
    int start = offs[node], end = offs[node + 1];
    float ad = ald[node];
    float* wn = wsh[nw];
    int* sn = ssh[nw];

    float ssum = 0.f;
    for (int j = start + lane; j < end; j += 64) {
        int idx = j - start;
        int s = csr[j];
        float e = als[s] + ad; e = e > 0.f ? e : NEG * e;
        float w = expf(e);
        ssum += w;
        if (idx < MAXD) { wn[idx] = w; sn[idx] = s; }
    }
    for (int mm = 32; mm; mm >>= 1) ssum += __shfl_xor(ssum, mm);
    float inv = 1.f / (ssum + 1e-16f);

    int g = lane / 10, c = lane % 10;           // 6 groups of 10 lanes; 60..63 idle
    const ushort4* h24 = (const ushort4*)h2b;
#define AGG2_FETCH(jv_, sv_, wv_) { \
        int idx_ = (jv_) - start; \
        if (idx_ < MAXD) { sv_ = sn[idx_]; wv_ = wn[idx_]; } \
        else { sv_ = csr[jv_]; float e_ = als[sv_] + ad; e_ = e_ > 0.f ? e_ : NEG * e_; wv_ = expf(e_); } }
    if (g < 6) {
        float4 acc = make_float4(0.f, 0.f, 0.f, 0.f);
        int j2 = start;
        for (; j2 + 12 <= end; j2 += 12) {
            int jA = j2 + g, jB = jA + 6;
            int sA, sB; float wA, wB;
            AGG2_FETCH(jA, sA, wA); AGG2_FETCH(jB, sB, wB);
            float4 hA = b2f4(h24[sA * 10 + c]); // 2 independent 80B gathers in flight
            float4 hB = b2f4(h24[sB * 10 + c]);
            FMA4(acc, wA, hA);
            FMA4(acc, wB, hB);
        }
        for (; j2 < end; j2 += 6) {
            int j = j2 + g;
            if (j < end) {
                int s; float w;
                AGG2_FETCH(j, s, w);
                float4 hv = b2f4(h24[s * 10 + c]);
                FMA4(acc, w, hv);
            }
        }
        red[nw][g][c] = acc;                    // same-wave DS ordering; no barrier needed
    }
#undef AGG2_FETCH

    if (lane < 16) {
        bool act = lane < 10;
        float4 o = make_float4(-1e30f, -1e30f, -1e30f, -1e30f);
        if (act) {
            float4 tot = make_float4(0.f, 0.f, 0.f, 0.f);
#pragma unroll
            for (int k = 0; k < 6; ++k) {
                float4 r = red[nw][k][lane];
                tot.x += r.x; tot.y += r.y; tot.z += r.z; tot.w += r.w;
            }
            float4 bb = ((const float4*)b)[lane];
            o.x = fmaf(tot.x, inv, bb.x); o.y = fmaf(tot.y, inv, bb.y);
            o.z = fmaf(tot.z, inv, bb.z); o.w = fmaf(tot.w, inv, bb.w);
        }
        // log_softmax over 40 classes within lanes 0..15 (10 active, 6 neutral)
        float mx = fmaxf(fmaxf(o.x, o.y), fmaxf(o.z, o.w));
#pragma unroll
        for (int mm = 1; mm <= 8; mm <<= 1) mx = fmaxf(mx, __shfl_xor(mx, mm));
        float es = (expf(o.x - mx) + expf(o.y - mx)) + (expf(o.z - mx) + expf(o.w - mx));
#pragma unroll
        for (int mm = 1; mm <= 8; mm <<= 1) es += __shfl_xor(es, mm);
        float lse = mx + logf(es);
        if (act) {
            float4 r;
            r.x = o.x - lse; r.y = o.y - lse; r.z = o.z - lse; r.w = o.w - lse;
            ((float4*)out)[node * 10 + lane] = r;
        }
    }
}

// ---------------- launch ----------------
extern "C" void kernel_launch(void* const* d_in, const int* in_sizes, int n_in,
                              void* d_out, int out_size, void* d_ws, size_t ws_size,
                              hipStream_t stream) {
    const float* x   = (const float*)d_in[0];
    const int*   ei  = (const int*)  d_in[1];
    const float* W1  = (const float*)d_in[2];
    const float* as1 = (const float*)d_in[3];
    const float* ad1 = (const float*)d_in[4];
    const float* b1  = (const float*)d_in[5];
    const float* W2  = (const float*)d_in[6];
    const float* as2 = (const float*)d_in[7];
    const float* ad2 = (const float*)d_in[8];
    const float* b2  = (const float*)d_in[9];
    float* out = (float*)d_out;

    // workspace carve-up
    char* p = (char*)d_ws;
    auto alloc = [&](size_t bytes) { void* r = (void*)p; p += (bytes + 255) & ~size_t(255); return r; };
    unsigned short* h1b   = (unsigned short*)alloc(sizeof(unsigned short) * NN * 128);
    unsigned short* heluB = (unsigned short*)alloc(sizeof(unsigned short) * NN * 128);
    unsigned short* h2b   = (unsigned short*)alloc(sizeof(unsigned short) * NN * 40);
    float* als1 = (float*)alloc(sizeof(float) * NN * 2);
    float* ald1 = (float*)alloc(sizeof(float) * NN * 2);
    float* als2 = (float*)alloc(sizeof(float) * NN);
    float* ald2 = (float*)alloc(sizeof(float) * NN);
    float* cs2  = (float*)alloc(sizeof(float) * 128);
    float* cd2  = (float*)alloc(sizeof(float) * 128);
    unsigned short* wh1 = (unsigned short*)alloc(sizeof(unsigned short) * 16384);
    unsigned short* wl1 = (unsigned short*)alloc(sizeof(unsigned short) * 16384);
    unsigned short* wh2 = (unsigned short*)alloc(sizeof(unsigned short) * 6144);
    unsigned short* wl2 = (unsigned short*)alloc(sizeof(unsigned short) * 6144);
    int*   deg  = (int*)  alloc(sizeof(int) * NN);
    int*   offs = (int*)  alloc(sizeof(int) * (NN + 1));
    int*   bsum = (int*)  alloc(sizeof(int) * 128);
    int*   rank = (int*)  alloc(sizeof(int) * E2);
    int*   csr  = (int*)  alloc(sizeof(int) * E2);

    // tiny precomputes (independent of CSR)
    cvec_kernel<<<1, 128, 0, stream>>>(W2, as2, ad2, cs2, cd2);
    prep1_kernel<<<64, 256, 0, stream>>>(W1, wh1, wl1);
    prep2_kernel<<<24, 256, 0, stream>>>(W2, wh2, wl2);

    // CSR build (dst-sorted adjacency) — single atomic pass
    hipMemsetAsync(deg, 0, sizeof(int) * NN, stream);
    rank_kernel<<<(E2 / 4 + 255) / 256, 256, 0, stream>>>(ei, deg, rank);
    scan1_kernel<<<98, 256, 0, stream>>>(bsum ? deg : deg, offs, bsum);
    scan2_kernel<<<1, 128, 0, stream>>>(bsum, offs);
    scan3_kernel<<<(NN + 255) / 256, 256, 0, stream>>>(offs, bsum);
    scatter_kernel<<<(E2 / 4 + 255) / 256, 256, 0, stream>>>(ei, rank, offs, csr);

    // Layer 1
    gemm1_mfma<<<1563, 256, 0, stream>>>(x, wh1, wl1, as1, ad1, h1b, als1, ald1);
    agg1_kernel<<<25000, 256, 0, stream>>>(offs, csr, als1, ald1, h1b, b1, cs2, cd2,
                                           heluB, als2, ald2);

    // Layer 2
    gemm2_mfma<<<1563, 256, 0, stream>>>(heluB, wh2, wl2, h2b);
    agg2_kernel<<<25000, 256, 0, stream>>>(offs, csr, als2, ald2, h2b, b2, out);
}